// Round 1
// baseline (260.211 us; speedup 1.0000x reference)
//
#include <hip/hip_runtime.h>

// ---------------------------------------------------------------------------
// TwoLayerGCN on MI355X (gfx950).
// B=4, N=2048, F=128, H=256, C=64.
//
// Math restructure (exact up to fp rounding):
//   deg_i = sum_j A_ij ; d_i = rsqrt(deg_i + 1)
//   w_ij  = [A_ij>0] * exp(lrelu(fs_i + fd_j)) * d_j * (1 + [i==j])
//   rs_i  = sum_j [A_ij>0] * exp(lrelu(fs_i + fd_j))
//   layer1: out1 = relu( (d_i/rs_i) * (W @ X) @ W1 + b1 )   (fused: T=W@X, T@W1)
//   layer2: node = (d_i/rs_i) * W2mat @ (out1 @ W2) + b2
//   graph  = sum_i node
// exp computed as exp2 of LOG2E-prescaled fs/fd (lrelu commutes with pos scale).
// No max-shift needed: score magnitudes bounded (~|13| layer1, ~1e-3 layer2).
// A (64MB) is read exactly once (kstats1) which emits a bitmask; all later
// passes read the 2MB bitmask.
// ---------------------------------------------------------------------------

typedef __attribute__((ext_vector_type(8))) short  s16x8;
typedef __attribute__((ext_vector_type(4))) float  f32x4;
typedef unsigned short u16;
typedef unsigned int   u32;
typedef unsigned long long u64;

#define LOG2E 1.4426950408889634f
#define NB 4
#define NN 2048
#define NF 128
#define NH 256
#define NC 64

__device__ __forceinline__ u16 f2bf(float f) {
    u32 x = __builtin_bit_cast(u32, f);
    return (u16)((x + 0x7fffu + ((x >> 16) & 1u)) >> 16);
}

// ---- prep: W1T bf16 [256][128], W2T bf16 [64][256] -------------------------
__global__ void kprep_w(const float* __restrict__ W1, const float* __restrict__ W2,
                        u16* __restrict__ W1T, u16* __restrict__ W2T) {
    int t = blockIdx.x * 256 + threadIdx.x;
    if (t < NF * NH) {                 // W1 [128][256] -> W1T [256][128]
        int k = t >> 8, c = t & 255;
        W1T[c * NF + k] = f2bf(W1[t]);
    }
    int t2 = t - NF * NH;
    if (t2 >= 0 && t2 < NH * NC) {     // W2 [256][64] -> W2T [64][256]
        int k = t2 >> 6, c = t2 & 63;
        W2T[c * NH + k] = f2bf(W2[t2]);
    }
}

// ---- prep: XT bf16 [B][128][2048] = transpose of X -------------------------
__global__ void kprep_xt(const float* __restrict__ X, u16* __restrict__ XT) {
    __shared__ float tile[64][132];
    int b = blockIdx.y, i0 = blockIdx.x * 64;
    for (int idx = threadIdx.x; idx < 64 * NF; idx += 256) {
        int r = idx >> 7, c = idx & 127;
        tile[r][c] = X[((size_t)b * NN + i0 + r) * NF + c];
    }
    __syncthreads();
    int c = threadIdx.x >> 1, half = threadIdx.x & 1;
    __attribute__((aligned(16))) u16 tmp[32];
#pragma unroll
    for (int q = 0; q < 32; q++) tmp[q] = f2bf(tile[half * 32 + q][c]);
    int4* dst = (int4*)&XT[((size_t)b * NF + c) * NN + i0 + half * 32];
    const int4* sv = (const int4*)tmp;
    dst[0] = sv[0]; dst[1] = sv[1]; dst[2] = sv[2]; dst[3] = sv[3];
}

// ---- dots layer1: FS1/FD1 = LOG2E * (X @ a_src / a_dst) --------------------
__global__ void kdots1(const float* __restrict__ X, const float* __restrict__ asrc,
                       const float* __restrict__ adst,
                       float* __restrict__ FS, float* __restrict__ FD) {
    int wv = threadIdx.x >> 6, l = threadIdx.x & 63;
    int row = blockIdx.x * 4 + wv;                    // 0..8191 (b*2048+i)
    float2 x  = *(const float2*)&X[(size_t)row * NF + l * 2];
    float2 as = *(const float2*)&asrc[l * 2];
    float2 ad = *(const float2*)&adst[l * 2];
    float s = x.x * as.x + x.y * as.y;
    float d = x.x * ad.x + x.y * ad.y;
#pragma unroll
    for (int o = 32; o > 0; o >>= 1) { s += __shfl_down(s, o); d += __shfl_down(d, o); }
    if (l == 0) { FS[row] = s * LOG2E; FD[row] = d * LOG2E; }
}

// ---- dots layer2 (256-dim from out1) ---------------------------------------
__global__ void kdots2(const float* __restrict__ out1, const float* __restrict__ asrc,
                       const float* __restrict__ adst,
                       float* __restrict__ FS, float* __restrict__ FD) {
    int wv = threadIdx.x >> 6, l = threadIdx.x & 63;
    int row = blockIdx.x * 4 + wv;
    float4 x  = *(const float4*)&out1[(size_t)row * NH + l * 4];
    float4 as = *(const float4*)&asrc[l * 4];
    float4 ad = *(const float4*)&adst[l * 4];
    float s = x.x * as.x + x.y * as.y + x.z * as.z + x.w * as.w;
    float d = x.x * ad.x + x.y * ad.y + x.z * ad.z + x.w * ad.w;
#pragma unroll
    for (int o = 32; o > 0; o >>= 1) { s += __shfl_down(s, o); d += __shfl_down(d, o); }
    if (l == 0) { FS[row] = s * LOG2E; FD[row] = d * LOG2E; }
}

// ---- stats layer1: the ONLY full read of A. deg->d, rs1->rowscale1, bitmask.
__global__ void kstats1(const float* __restrict__ A, const float* __restrict__ FS,
                        const float* __restrict__ FD,
                        float* __restrict__ dvec, float* __restrict__ rsc1,
                        u64* __restrict__ bm) {
    int row = blockIdx.x;                      // 0..8191
    int b = row >> 11;
    const float* Arow = A + (size_t)row * NN;
    const float* FDb = FD + (b << 11);
    float fs = FS[row];
    int l = threadIdx.x & 63, wv = threadIdx.x >> 6;
    float deg = 0.f, rs = 0.f;
#pragma unroll
    for (int e = 0; e < 8; e++) {
        int j = e * 256 + threadIdx.x;         // wave-consecutive j for ballot
        float a = Arow[j];
        float s = fs + FDb[j];
        deg += a;
        bool nb = a > 0.f;
        float w = exp2f(fmaxf(s, 0.2f * s));
        rs += nb ? w : 0.f;
        u64 m = __ballot(nb);
        if (l == 0) bm[(size_t)row * 32 + e * 4 + wv] = m;
    }
    __shared__ float red[2][4];
#pragma unroll
    for (int o = 32; o > 0; o >>= 1) { deg += __shfl_down(deg, o); rs += __shfl_down(rs, o); }
    if (l == 0) { red[0][wv] = deg; red[1][wv] = rs; }
    __syncthreads();
    if (threadIdx.x == 0) {
        float D = red[0][0] + red[0][1] + red[0][2] + red[0][3];
        float R = red[1][0] + red[1][1] + red[1][2] + red[1][3];
        float dv = rsqrtf(D + 1.0f);
        dvec[row] = dv;
        rsc1[row] = dv / R;
    }
}

// ---- stats layer2: rs2 from bitmask ----------------------------------------
__global__ void kstats2(const u64* __restrict__ bm, const float* __restrict__ FS,
                        const float* __restrict__ FD, const float* __restrict__ dvec,
                        float* __restrict__ rsc2) {
    int wv = threadIdx.x >> 6, l = threadIdx.x & 63;
    int row = blockIdx.x * 4 + wv;
    int b = row >> 11;
    const float* FDb = FD + (b << 11);
    float fs = FS[row], rs = 0.f;
    for (int e = 0; e < 32; e++) {
        u64 m = bm[(size_t)row * 32 + e];
        float fd = FDb[e * 64 + l];
        float s = fs + fd;
        float w = exp2f(fmaxf(s, 0.2f * s));
        rs += ((m >> l) & 1ull) ? w : 0.f;
    }
#pragma unroll
    for (int o = 32; o > 0; o >>= 1) rs += __shfl_down(rs, o);
    if (l == 0) rsc2[row] = dvec[row] / rs;
}

// ---- fused layer1 spmm: out1 = relu(rowscale * (W@X)@W1 + b1) --------------
__global__ __launch_bounds__(512) void kspmm1(
    const u32* __restrict__ bm32, const float* __restrict__ FS,
    const float* __restrict__ FD, const float* __restrict__ dvec,
    const float* __restrict__ rsc1, const u16* __restrict__ XT,
    const u16* __restrict__ W1T, const float* __restrict__ b1,
    float* __restrict__ out1) {
    const int b = blockIdx.y;
    const int i0 = blockIdx.x * 32;
    const int t = threadIdx.x;
    const int l = t & 63, wv = t >> 6;
    const int g = l >> 4, li = l & 15;

    __shared__ __attribute__((aligned(16))) u16 xlds[128][40];
    __shared__ __attribute__((aligned(16))) u16 wlds[32][40];
    __shared__ __attribute__((aligned(16))) float tlds[32][132];

    const int mg = wv & 1;          // stage1 row group (16 rows)
    const int xg = wv >> 1;         // stage1 X-col group (32 cols)

    const int sr = (t * 2) >> 5;    // w-staging row 0..31
    const int sk = (t * 2) & 31;    // w-staging col (even)
    const int grow = i0 + sr;
    const float fs_r = FS[(b << 11) + grow];
    const float* FDb = FD + (b << 11);
    const float* Db  = dvec + (b << 11);
    const u32* bmrow = bm32 + ((size_t)((b << 11) + grow)) * 64;
    const u16* XTb = XT + (size_t)b * NF * NN;

    f32x4 zero = {0.f, 0.f, 0.f, 0.f};
    f32x4 acc0 = zero, acc1 = zero;

    for (int k0 = 0; k0 < NN; k0 += 32) {
        __syncthreads();
        {   // stage X tile: 128 rows x 32 halves (one 16B chunk per thread)
            int c = t >> 2, seg = t & 3;
            int4 v = *(const int4*)(XTb + (size_t)c * NN + k0 + seg * 8);
            *(int4*)&xlds[c][seg * 8] = v;
        }
        {   // stage w tile: 2 elems per thread
            u32 word = bmrow[k0 >> 5];
            int j = k0 + sk;
            float2 fd2 = *(const float2*)&FDb[j];
            float2 dj2 = *(const float2*)&Db[j];
            float s0 = fs_r + fd2.x, s1 = fs_r + fd2.y;
            float w0 = exp2f(fmaxf(s0, 0.2f * s0)) * dj2.x;
            float w1 = exp2f(fmaxf(s1, 0.2f * s1)) * dj2.y;
            if (j == grow)     w0 *= 2.f;     // (A+I) diagonal
            if (j + 1 == grow) w1 *= 2.f;
            w0 = ((word >> sk) & 1u)       ? w0 : 0.f;
            w1 = ((word >> (sk + 1)) & 1u) ? w1 : 0.f;
            u32 pack = (u32)f2bf(w0) | ((u32)f2bf(w1) << 16);
            *(u32*)&wlds[sr][sk] = pack;
        }
        __syncthreads();
        s16x8 af  = *(const s16x8*)&wlds[mg * 16 + li][g * 8];
        s16x8 bf0 = *(const s16x8*)&xlds[xg * 32 + li][g * 8];
        s16x8 bf1 = *(const s16x8*)&xlds[xg * 32 + 16 + li][g * 8];
        acc0 = __builtin_amdgcn_mfma_f32_16x16x32_bf16(af, bf0, acc0, 0, 0, 0);
        acc1 = __builtin_amdgcn_mfma_f32_16x16x32_bf16(af, bf1, acc1, 0, 0, 0);
    }
    // T = W@X into LDS (f32)
#pragma unroll
    for (int r = 0; r < 4; r++) {
        tlds[mg * 16 + g * 4 + r][xg * 32 + li]      = acc0[r];
        tlds[mg * 16 + g * 4 + r][xg * 32 + 16 + li] = acc1[r];
    }
    __syncthreads();
    // stage 2: out1_block = T[32][128] @ W1[128][256]
    const int mt = wv & 1;          // row tile
    const int cg = wv >> 1;         // col group (64 cols)
    f32x4 acc2[4] = {zero, zero, zero, zero};
    for (int k2 = 0; k2 < NF; k2 += 32) {
        float4 t0 = *(const float4*)&tlds[mt * 16 + li][k2 + g * 8];
        float4 t1 = *(const float4*)&tlds[mt * 16 + li][k2 + g * 8 + 4];
        s16x8 af2;
        af2[0] = (short)f2bf(t0.x); af2[1] = (short)f2bf(t0.y);
        af2[2] = (short)f2bf(t0.z); af2[3] = (short)f2bf(t0.w);
        af2[4] = (short)f2bf(t1.x); af2[5] = (short)f2bf(t1.y);
        af2[6] = (short)f2bf(t1.z); af2[7] = (short)f2bf(t1.w);
#pragma unroll
        for (int nf = 0; nf < 4; nf++) {
            const u16* wp = W1T + (size_t)(cg * 64 + nf * 16 + li) * NF + k2 + g * 8;
            s16x8 bf2 = *(const s16x8*)wp;
            acc2[nf] = __builtin_amdgcn_mfma_f32_16x16x32_bf16(af2, bf2, acc2[nf], 0, 0, 0);
        }
    }
#pragma unroll
    for (int r = 0; r < 4; r++) {
        int i = i0 + mt * 16 + g * 4 + r;
        float rsc = rsc1[(b << 11) + i];
#pragma unroll
        for (int nf = 0; nf < 4; nf++) {
            int c = cg * 64 + nf * 16 + li;
            float v = acc2[nf][r] * rsc + b1[c];
            out1[((size_t)(b << 11) + i) * NH + c] = fmaxf(v, 0.f);
        }
    }
}

// ---- gemm2: OW2T bf16 [B][64][2048] = (out1 @ W2)^T ------------------------
__global__ __launch_bounds__(256) void kgemm2(const float* __restrict__ out1,
                                              const u16* __restrict__ W2T,
                                              u16* __restrict__ OW2T) {
    const int b = blockIdx.y;
    const int j0 = blockIdx.x * 32;
    const int t = threadIdx.x;
    const int l = t & 63, wv = t >> 6;
    const int g = l >> 4, li = l & 15;
    const int mt = wv & 1, cg = wv >> 1;      // 2 row tiles x 2 col groups(32)
    f32x4 zero = {0.f, 0.f, 0.f, 0.f};
    f32x4 acc[2] = {zero, zero};
    for (int k0 = 0; k0 < NH; k0 += 32) {
        const float* src = out1 + ((size_t)(b << 11) + j0 + mt * 16 + li) * NH + k0 + g * 8;
        float4 v0 = *(const float4*)src;
        float4 v1 = *(const float4*)(src + 4);
        s16x8 af;
        af[0] = (short)f2bf(v0.x); af[1] = (short)f2bf(v0.y);
        af[2] = (short)f2bf(v0.z); af[3] = (short)f2bf(v0.w);
        af[4] = (short)f2bf(v1.x); af[5] = (short)f2bf(v1.y);
        af[6] = (short)f2bf(v1.z); af[7] = (short)f2bf(v1.w);
#pragma unroll
        for (int nf = 0; nf < 2; nf++) {
            s16x8 bf = *(const s16x8*)&W2T[(size_t)(cg * 32 + nf * 16 + li) * NH + k0 + g * 8];
            acc[nf] = __builtin_amdgcn_mfma_f32_16x16x32_bf16(af, bf, acc[nf], 0, 0, 0);
        }
    }
#pragma unroll
    for (int nf = 0; nf < 2; nf++) {
        int c = cg * 32 + nf * 16 + li;
        uint2 pk;
        pk.x = (u32)f2bf(acc[nf][0]) | ((u32)f2bf(acc[nf][1]) << 16);
        pk.y = (u32)f2bf(acc[nf][2]) | ((u32)f2bf(acc[nf][3]) << 16);
        *(uint2*)&OW2T[((size_t)b * NC + c) * NN + j0 + mt * 16 + g * 4] = pk;
    }
}

// ---- layer2 spmm: node = rowscale2 * W2mat @ OW2 + b2 ----------------------
__global__ __launch_bounds__(512) void kspmm2(
    const u32* __restrict__ bm32, const float* __restrict__ FS,
    const float* __restrict__ FD, const float* __restrict__ dvec,
    const float* __restrict__ rsc2, const u16* __restrict__ OW2T,
    const float* __restrict__ b2, float* __restrict__ node) {
    const int b = blockIdx.y;
    const int i0 = blockIdx.x * 32;
    const int t = threadIdx.x;
    const int l = t & 63, wv = t >> 6;
    const int g = l >> 4, li = l & 15;
    const int mg = wv & 1;            // 2 row groups
    const int cg = wv >> 1;           // 4 col groups x 16 = 64

    __shared__ __attribute__((aligned(16))) u16 olds[64][40];
    __shared__ __attribute__((aligned(16))) u16 wlds[32][40];

    const int sr = (t * 2) >> 5;
    const int sk = (t * 2) & 31;
    const int grow = i0 + sr;
    const float fs_r = FS[(b << 11) + grow];
    const float* FDb = FD + (b << 11);
    const float* Db  = dvec + (b << 11);
    const u32* bmrow = bm32 + ((size_t)((b << 11) + grow)) * 64;
    const u16* Ob = OW2T + (size_t)b * NC * NN;

    f32x4 acc = {0.f, 0.f, 0.f, 0.f};
    for (int k0 = 0; k0 < NN; k0 += 32) {
        __syncthreads();
        if (t < 256) {
            int c = t >> 2, seg = t & 3;
            int4 v = *(const int4*)(Ob + (size_t)c * NN + k0 + seg * 8);
            *(int4*)&olds[c][seg * 8] = v;
        }
        {
            u32 word = bmrow[k0 >> 5];
            int j = k0 + sk;
            float2 fd2 = *(const float2*)&FDb[j];
            float2 dj2 = *(const float2*)&Db[j];
            float s0 = fs_r + fd2.x, s1 = fs_r + fd2.y;
            float w0 = exp2f(fmaxf(s0, 0.2f * s0)) * dj2.x;
            float w1 = exp2f(fmaxf(s1, 0.2f * s1)) * dj2.y;
            if (j == grow)     w0 *= 2.f;
            if (j + 1 == grow) w1 *= 2.f;
            w0 = ((word >> sk) & 1u)       ? w0 : 0.f;
            w1 = ((word >> (sk + 1)) & 1u) ? w1 : 0.f;
            u32 pack = (u32)f2bf(w0) | ((u32)f2bf(w1) << 16);
            *(u32*)&wlds[sr][sk] = pack;
        }
        __syncthreads();
        s16x8 af = *(const s16x8*)&wlds[mg * 16 + li][g * 8];
        s16x8 bf = *(const s16x8*)&olds[cg * 16 + li][g * 8];
        acc = __builtin_amdgcn_mfma_f32_16x16x32_bf16(af, bf, acc, 0, 0, 0);
    }
#pragma unroll
    for (int r = 0; r < 4; r++) {
        int i = i0 + mg * 16 + g * 4 + r;
        float rsc = rsc2[(b << 11) + i];
        int c = cg * 16 + li;
        node[((size_t)(b << 11) + i) * NC + c] = acc[r] * rsc + b2[c];
    }
}

// ---- graph scores: sum over nodes ------------------------------------------
__global__ void kgraph(const float* __restrict__ node, float* __restrict__ graph) {
    int b = blockIdx.x;
    int c = threadIdx.x & 63, ch = threadIdx.x >> 6;
    float s = 0.f;
    for (int i = ch; i < NN; i += 4) s += node[((size_t)(b << 11) + i) * NC + c];
    __shared__ float red[4][64];
    red[ch][c] = s;
    __syncthreads();
    if (ch == 0) graph[b * NC + c] = red[0][c] + red[1][c] + red[2][c] + red[3][c];
}

extern "C" void kernel_launch(void* const* d_in, const int* in_sizes, int n_in,
                              void* d_out, int out_size, void* d_ws, size_t ws_size,
                              hipStream_t stream) {
    const float* X   = (const float*)d_in[0];
    const float* A   = (const float*)d_in[1];
    const float* a1s = (const float*)d_in[2];
    const float* a1d = (const float*)d_in[3];
    const float* W1  = (const float*)d_in[4];
    const float* b1  = (const float*)d_in[5];
    const float* a2s = (const float*)d_in[6];
    const float* a2d = (const float*)d_in[7];
    const float* W2  = (const float*)d_in[8];
    const float* b2  = (const float*)d_in[9];

    float* node  = (float*)d_out;                 // [4][2048][64]
    float* graph = node + (size_t)NB * NN * NC;   // [4][64]

    char* w = (char*)d_ws;
    float* FS1  = (float*)w; w += NB * NN * 4;
    float* FD1  = (float*)w; w += NB * NN * 4;
    float* FS2  = (float*)w; w += NB * NN * 4;
    float* FD2  = (float*)w; w += NB * NN * 4;
    float* dvec = (float*)w; w += NB * NN * 4;
    float* rsc1 = (float*)w; w += NB * NN * 4;
    float* rsc2 = (float*)w; w += NB * NN * 4;
    u64*  bm    = (u64*)w;  w += (size_t)NB * NN * 32 * 8;    // 2 MB
    u16*  XT    = (u16*)w;  w += (size_t)NB * NF * NN * 2;    // 2 MB
    float* out1 = (float*)w; w += (size_t)NB * NN * NH * 4;   // 8 MB
    u16*  OW2T  = (u16*)w;  w += (size_t)NB * NC * NN * 2;    // 1 MB
    u16*  W1T   = (u16*)w;  w += NH * NF * 2;
    u16*  W2T   = (u16*)w;  w += NC * NH * 2;

    kprep_w <<<192, 256, 0, stream>>>(W1, W2, W1T, W2T);
    kprep_xt<<<dim3(32, NB), 256, 0, stream>>>(X, XT);
    kdots1  <<<NB * NN / 4, 256, 0, stream>>>(X, a1s, a1d, FS1, FD1);
    kstats1 <<<NB * NN, 256, 0, stream>>>(A, FS1, FD1, dvec, rsc1, bm);
    kspmm1  <<<dim3(NN / 32, NB), 512, 0, stream>>>((const u32*)bm, FS1, FD1, dvec,
                                                    rsc1, XT, W1T, b1, out1);
    kdots2  <<<NB * NN / 4, 256, 0, stream>>>(out1, a2s, a2d, FS2, FD2);
    kstats2 <<<NB * NN / 4, 256, 0, stream>>>(bm, FS2, FD2, dvec, rsc2);
    kgemm2  <<<dim3(NN / 32, NB), 256, 0, stream>>>(out1, W2T, OW2T);
    kspmm2  <<<dim3(NN / 32, NB), 512, 0, stream>>>((const u32*)bm, FS2, FD2, dvec,
                                                    rsc2, OW2T, b2, node);
    kgraph  <<<NB, 256, 0, stream>>>(node, graph);
}

// Round 2
// 144.793 us; speedup vs baseline: 1.7971x; 1.7971x over previous
//
#include <hip/hip_runtime.h>

// ---------------------------------------------------------------------------
// TwoLayerGCN on MI355X (gfx950).
// B=4, N=2048, F=128, H=256, C=64.
//
// Math restructure (exact up to fp rounding):
//   deg_i = sum_j A_ij ; d_i = rsqrt(deg_i + 1)
//   w_ij  = [A_ij>0] * exp(lrelu(fs_i + fd_j)) * d_j * (1 + [i==j])
//   rs_i  = sum_j [A_ij>0] * exp(lrelu(fs_i + fd_j))
//   layer1: out1 = relu( (d_i/rs_i) * (W @ X) @ W1 + b1 )   (fused: T=W@X, T@W1)
//   layer2: node = (d_i/rs_i) * W2mat @ (out1 @ W2) + b2
//   graph  = sum_i node   (partials fused into kspmm2; tiny reduce kernel)
// exp computed as exp2 of LOG2E-prescaled fs/fd (lrelu commutes with pos scale).
// A (64MB) is read exactly once (kstats1) which emits a bitmask; all later
// passes read the 2MB bitmask.
// R1 fix: old kgraph was 4 blocks / latency-bound = 122us (47% of wall).
// Graph partials now computed in kspmm2 registers; kgraph2 reduces 64KB.
// ---------------------------------------------------------------------------

typedef __attribute__((ext_vector_type(8))) short  s16x8;
typedef __attribute__((ext_vector_type(4))) float  f32x4;
typedef unsigned short u16;
typedef unsigned int   u32;
typedef unsigned long long u64;

#define LOG2E 1.4426950408889634f
#define NB 4
#define NN 2048
#define NF 128
#define NH 256
#define NC 64

__device__ __forceinline__ u16 f2bf(float f) {
    u32 x = __builtin_bit_cast(u32, f);
    return (u16)((x + 0x7fffu + ((x >> 16) & 1u)) >> 16);
}

// ---- prep: W1T bf16 [256][128], W2T bf16 [64][256] -------------------------
__global__ void kprep_w(const float* __restrict__ W1, const float* __restrict__ W2,
                        u16* __restrict__ W1T, u16* __restrict__ W2T) {
    int t = blockIdx.x * 256 + threadIdx.x;
    if (t < NF * NH) {                 // W1 [128][256] -> W1T [256][128]
        int k = t >> 8, c = t & 255;
        W1T[c * NF + k] = f2bf(W1[t]);
    }
    int t2 = t - NF * NH;
    if (t2 >= 0 && t2 < NH * NC) {     // W2 [256][64] -> W2T [64][256]
        int k = t2 >> 6, c = t2 & 63;
        W2T[c * NH + k] = f2bf(W2[t2]);
    }
}

// ---- prep: XT bf16 [B][128][2048] = transpose of X -------------------------
__global__ void kprep_xt(const float* __restrict__ X, u16* __restrict__ XT) {
    __shared__ float tile[64][132];
    int b = blockIdx.y, i0 = blockIdx.x * 64;
    for (int idx = threadIdx.x; idx < 64 * NF; idx += 256) {
        int r = idx >> 7, c = idx & 127;
        tile[r][c] = X[((size_t)b * NN + i0 + r) * NF + c];
    }
    __syncthreads();
    int c = threadIdx.x >> 1, half = threadIdx.x & 1;
    __attribute__((aligned(16))) u16 tmp[32];
#pragma unroll
    for (int q = 0; q < 32; q++) tmp[q] = f2bf(tile[half * 32 + q][c]);
    int4* dst = (int4*)&XT[((size_t)b * NF + c) * NN + i0 + half * 32];
    const int4* sv = (const int4*)tmp;
    dst[0] = sv[0]; dst[1] = sv[1]; dst[2] = sv[2]; dst[3] = sv[3];
}

// ---- dots layer1: FS1/FD1 = LOG2E * (X @ a_src / a_dst) --------------------
__global__ void kdots1(const float* __restrict__ X, const float* __restrict__ asrc,
                       const float* __restrict__ adst,
                       float* __restrict__ FS, float* __restrict__ FD) {
    int wv = threadIdx.x >> 6, l = threadIdx.x & 63;
    int row = blockIdx.x * 4 + wv;                    // 0..8191 (b*2048+i)
    float2 x  = *(const float2*)&X[(size_t)row * NF + l * 2];
    float2 as = *(const float2*)&asrc[l * 2];
    float2 ad = *(const float2*)&adst[l * 2];
    float s = x.x * as.x + x.y * as.y;
    float d = x.x * ad.x + x.y * ad.y;
#pragma unroll
    for (int o = 32; o > 0; o >>= 1) { s += __shfl_down(s, o); d += __shfl_down(d, o); }
    if (l == 0) { FS[row] = s * LOG2E; FD[row] = d * LOG2E; }
}

// ---- dots layer2 (256-dim from out1) ---------------------------------------
__global__ void kdots2(const float* __restrict__ out1, const float* __restrict__ asrc,
                       const float* __restrict__ adst,
                       float* __restrict__ FS, float* __restrict__ FD) {
    int wv = threadIdx.x >> 6, l = threadIdx.x & 63;
    int row = blockIdx.x * 4 + wv;
    float4 x  = *(const float4*)&out1[(size_t)row * NH + l * 4];
    float4 as = *(const float4*)&asrc[l * 4];
    float4 ad = *(const float4*)&adst[l * 4];
    float s = x.x * as.x + x.y * as.y + x.z * as.z + x.w * as.w;
    float d = x.x * ad.x + x.y * ad.y + x.z * ad.z + x.w * ad.w;
#pragma unroll
    for (int o = 32; o > 0; o >>= 1) { s += __shfl_down(s, o); d += __shfl_down(d, o); }
    if (l == 0) { FS[row] = s * LOG2E; FD[row] = d * LOG2E; }
}

// ---- stats layer1: the ONLY full read of A. deg->d, rs1->rowscale1, bitmask.
__global__ void kstats1(const float* __restrict__ A, const float* __restrict__ FS,
                        const float* __restrict__ FD,
                        float* __restrict__ dvec, float* __restrict__ rsc1,
                        u64* __restrict__ bm) {
    int row = blockIdx.x;                      // 0..8191
    int b = row >> 11;
    const float* Arow = A + (size_t)row * NN;
    const float* FDb = FD + (b << 11);
    float fs = FS[row];
    int l = threadIdx.x & 63, wv = threadIdx.x >> 6;
    float deg = 0.f, rs = 0.f;
#pragma unroll
    for (int e = 0; e < 8; e++) {
        int j = e * 256 + threadIdx.x;         // wave-consecutive j for ballot
        float a = Arow[j];
        float s = fs + FDb[j];
        deg += a;
        bool nb = a > 0.f;
        float w = exp2f(fmaxf(s, 0.2f * s));
        rs += nb ? w : 0.f;
        u64 m = __ballot(nb);
        if (l == 0) bm[(size_t)row * 32 + e * 4 + wv] = m;
    }
    __shared__ float red[2][4];
#pragma unroll
    for (int o = 32; o > 0; o >>= 1) { deg += __shfl_down(deg, o); rs += __shfl_down(rs, o); }
    if (l == 0) { red[0][wv] = deg; red[1][wv] = rs; }
    __syncthreads();
    if (threadIdx.x == 0) {
        float D = red[0][0] + red[0][1] + red[0][2] + red[0][3];
        float R = red[1][0] + red[1][1] + red[1][2] + red[1][3];
        float dv = rsqrtf(D + 1.0f);
        dvec[row] = dv;
        rsc1[row] = dv / R;
    }
}

// ---- stats layer2: rs2 from bitmask ----------------------------------------
__global__ void kstats2(const u64* __restrict__ bm, const float* __restrict__ FS,
                        const float* __restrict__ FD, const float* __restrict__ dvec,
                        float* __restrict__ rsc2) {
    int wv = threadIdx.x >> 6, l = threadIdx.x & 63;
    int row = blockIdx.x * 4 + wv;
    int b = row >> 11;
    const float* FDb = FD + (b << 11);
    float fs = FS[row], rs = 0.f;
    for (int e = 0; e < 32; e++) {
        u64 m = bm[(size_t)row * 32 + e];
        float fd = FDb[e * 64 + l];
        float s = fs + fd;
        float w = exp2f(fmaxf(s, 0.2f * s));
        rs += ((m >> l) & 1ull) ? w : 0.f;
    }
#pragma unroll
    for (int o = 32; o > 0; o >>= 1) rs += __shfl_down(rs, o);
    if (l == 0) rsc2[row] = dvec[row] / rs;
}

// ---- fused layer1 spmm: out1 = relu(rowscale * (W@X)@W1 + b1) --------------
__global__ __launch_bounds__(512) void kspmm1(
    const u32* __restrict__ bm32, const float* __restrict__ FS,
    const float* __restrict__ FD, const float* __restrict__ dvec,
    const float* __restrict__ rsc1, const u16* __restrict__ XT,
    const u16* __restrict__ W1T, const float* __restrict__ b1,
    float* __restrict__ out1) {
    const int b = blockIdx.y;
    const int i0 = blockIdx.x * 32;
    const int t = threadIdx.x;
    const int l = t & 63, wv = t >> 6;
    const int g = l >> 4, li = l & 15;

    __shared__ __attribute__((aligned(16))) u16 xlds[128][40];
    __shared__ __attribute__((aligned(16))) u16 wlds[32][40];
    __shared__ __attribute__((aligned(16))) float tlds[32][132];

    const int mg = wv & 1;          // stage1 row group (16 rows)
    const int xg = wv >> 1;         // stage1 X-col group (32 cols)

    const int sr = (t * 2) >> 5;    // w-staging row 0..31
    const int sk = (t * 2) & 31;    // w-staging col (even)
    const int grow = i0 + sr;
    const float fs_r = FS[(b << 11) + grow];
    const float* FDb = FD + (b << 11);
    const float* Db  = dvec + (b << 11);
    const u32* bmrow = bm32 + ((size_t)((b << 11) + grow)) * 64;
    const u16* XTb = XT + (size_t)b * NF * NN;

    f32x4 zero = {0.f, 0.f, 0.f, 0.f};
    f32x4 acc0 = zero, acc1 = zero;

    for (int k0 = 0; k0 < NN; k0 += 32) {
        __syncthreads();
        {   // stage X tile: 128 rows x 32 halves (one 16B chunk per thread)
            int c = t >> 2, seg = t & 3;
            int4 v = *(const int4*)(XTb + (size_t)c * NN + k0 + seg * 8);
            *(int4*)&xlds[c][seg * 8] = v;
        }
        {   // stage w tile: 2 elems per thread
            u32 word = bmrow[k0 >> 5];
            int j = k0 + sk;
            float2 fd2 = *(const float2*)&FDb[j];
            float2 dj2 = *(const float2*)&Db[j];
            float s0 = fs_r + fd2.x, s1 = fs_r + fd2.y;
            float w0 = exp2f(fmaxf(s0, 0.2f * s0)) * dj2.x;
            float w1 = exp2f(fmaxf(s1, 0.2f * s1)) * dj2.y;
            if (j == grow)     w0 *= 2.f;     // (A+I) diagonal
            if (j + 1 == grow) w1 *= 2.f;
            w0 = ((word >> sk) & 1u)       ? w0 : 0.f;
            w1 = ((word >> (sk + 1)) & 1u) ? w1 : 0.f;
            u32 pack = (u32)f2bf(w0) | ((u32)f2bf(w1) << 16);
            *(u32*)&wlds[sr][sk] = pack;
        }
        __syncthreads();
        s16x8 af  = *(const s16x8*)&wlds[mg * 16 + li][g * 8];
        s16x8 bf0 = *(const s16x8*)&xlds[xg * 32 + li][g * 8];
        s16x8 bf1 = *(const s16x8*)&xlds[xg * 32 + 16 + li][g * 8];
        acc0 = __builtin_amdgcn_mfma_f32_16x16x32_bf16(af, bf0, acc0, 0, 0, 0);
        acc1 = __builtin_amdgcn_mfma_f32_16x16x32_bf16(af, bf1, acc1, 0, 0, 0);
    }
    // T = W@X into LDS (f32)
#pragma unroll
    for (int r = 0; r < 4; r++) {
        tlds[mg * 16 + g * 4 + r][xg * 32 + li]      = acc0[r];
        tlds[mg * 16 + g * 4 + r][xg * 32 + 16 + li] = acc1[r];
    }
    __syncthreads();
    // stage 2: out1_block = T[32][128] @ W1[128][256]
    const int mt = wv & 1;          // row tile
    const int cg = wv >> 1;         // col group (64 cols)
    f32x4 acc2[4] = {zero, zero, zero, zero};
    for (int k2 = 0; k2 < NF; k2 += 32) {
        float4 t0 = *(const float4*)&tlds[mt * 16 + li][k2 + g * 8];
        float4 t1 = *(const float4*)&tlds[mt * 16 + li][k2 + g * 8 + 4];
        s16x8 af2;
        af2[0] = (short)f2bf(t0.x); af2[1] = (short)f2bf(t0.y);
        af2[2] = (short)f2bf(t0.z); af2[3] = (short)f2bf(t0.w);
        af2[4] = (short)f2bf(t1.x); af2[5] = (short)f2bf(t1.y);
        af2[6] = (short)f2bf(t1.z); af2[7] = (short)f2bf(t1.w);
#pragma unroll
        for (int nf = 0; nf < 4; nf++) {
            const u16* wp = W1T + (size_t)(cg * 64 + nf * 16 + li) * NF + k2 + g * 8;
            s16x8 bf2 = *(const s16x8*)wp;
            acc2[nf] = __builtin_amdgcn_mfma_f32_16x16x32_bf16(af2, bf2, acc2[nf], 0, 0, 0);
        }
    }
#pragma unroll
    for (int r = 0; r < 4; r++) {
        int i = i0 + mt * 16 + g * 4 + r;
        float rsc = rsc1[(b << 11) + i];
#pragma unroll
        for (int nf = 0; nf < 4; nf++) {
            int c = cg * 64 + nf * 16 + li;
            float v = acc2[nf][r] * rsc + b1[c];
            out1[((size_t)(b << 11) + i) * NH + c] = fmaxf(v, 0.f);
        }
    }
}

// ---- gemm2: OW2T bf16 [B][64][2048] = (out1 @ W2)^T ------------------------
__global__ __launch_bounds__(256) void kgemm2(const float* __restrict__ out1,
                                              const u16* __restrict__ W2T,
                                              u16* __restrict__ OW2T) {
    const int b = blockIdx.y;
    const int j0 = blockIdx.x * 32;
    const int t = threadIdx.x;
    const int l = t & 63, wv = t >> 6;
    const int g = l >> 4, li = l & 15;
    const int mt = wv & 1, cg = wv >> 1;      // 2 row tiles x 2 col groups(32)
    f32x4 zero = {0.f, 0.f, 0.f, 0.f};
    f32x4 acc[2] = {zero, zero};
    for (int k0 = 0; k0 < NH; k0 += 32) {
        const float* src = out1 + ((size_t)(b << 11) + j0 + mt * 16 + li) * NH + k0 + g * 8;
        float4 v0 = *(const float4*)src;
        float4 v1 = *(const float4*)(src + 4);
        s16x8 af;
        af[0] = (short)f2bf(v0.x); af[1] = (short)f2bf(v0.y);
        af[2] = (short)f2bf(v0.z); af[3] = (short)f2bf(v0.w);
        af[4] = (short)f2bf(v1.x); af[5] = (short)f2bf(v1.y);
        af[6] = (short)f2bf(v1.z); af[7] = (short)f2bf(v1.w);
#pragma unroll
        for (int nf = 0; nf < 2; nf++) {
            s16x8 bf = *(const s16x8*)&W2T[(size_t)(cg * 32 + nf * 16 + li) * NH + k0 + g * 8];
            acc[nf] = __builtin_amdgcn_mfma_f32_16x16x32_bf16(af, bf, acc[nf], 0, 0, 0);
        }
    }
#pragma unroll
    for (int nf = 0; nf < 2; nf++) {
        int c = cg * 32 + nf * 16 + li;
        uint2 pk;
        pk.x = (u32)f2bf(acc[nf][0]) | ((u32)f2bf(acc[nf][1]) << 16);
        pk.y = (u32)f2bf(acc[nf][2]) | ((u32)f2bf(acc[nf][3]) << 16);
        *(uint2*)&OW2T[((size_t)b * NC + c) * NN + j0 + mt * 16 + g * 4] = pk;
    }
}

// ---- layer2 spmm: node = rowscale2 * W2mat @ OW2 + b2; graph partials ------
__global__ __launch_bounds__(512) void kspmm2(
    const u32* __restrict__ bm32, const float* __restrict__ FS,
    const float* __restrict__ FD, const float* __restrict__ dvec,
    const float* __restrict__ rsc2, const u16* __restrict__ OW2T,
    const float* __restrict__ b2, float* __restrict__ node,
    float* __restrict__ gpart) {
    const int b = blockIdx.y;
    const int i0 = blockIdx.x * 32;
    const int t = threadIdx.x;
    const int l = t & 63, wv = t >> 6;
    const int g = l >> 4, li = l & 15;
    const int mg = wv & 1;            // 2 row groups
    const int cg = wv >> 1;           // 4 col groups x 16 = 64

    __shared__ __attribute__((aligned(16))) u16 olds[64][40];
    __shared__ __attribute__((aligned(16))) u16 wlds[32][40];

    const int sr = (t * 2) >> 5;
    const int sk = (t * 2) & 31;
    const int grow = i0 + sr;
    const float fs_r = FS[(b << 11) + grow];
    const float* FDb = FD + (b << 11);
    const float* Db  = dvec + (b << 11);
    const u32* bmrow = bm32 + ((size_t)((b << 11) + grow)) * 64;
    const u16* Ob = OW2T + (size_t)b * NC * NN;

    f32x4 acc = {0.f, 0.f, 0.f, 0.f};
    for (int k0 = 0; k0 < NN; k0 += 32) {
        __syncthreads();
        if (t < 256) {
            int c = t >> 2, seg = t & 3;
            int4 v = *(const int4*)(Ob + (size_t)c * NN + k0 + seg * 8);
            *(int4*)&olds[c][seg * 8] = v;
        }
        {
            u32 word = bmrow[k0 >> 5];
            int j = k0 + sk;
            float2 fd2 = *(const float2*)&FDb[j];
            float2 dj2 = *(const float2*)&Db[j];
            float s0 = fs_r + fd2.x, s1 = fs_r + fd2.y;
            float w0 = exp2f(fmaxf(s0, 0.2f * s0)) * dj2.x;
            float w1 = exp2f(fmaxf(s1, 0.2f * s1)) * dj2.y;
            if (j == grow)     w0 *= 2.f;
            if (j + 1 == grow) w1 *= 2.f;
            w0 = ((word >> sk) & 1u)       ? w0 : 0.f;
            w1 = ((word >> (sk + 1)) & 1u) ? w1 : 0.f;
            u32 pack = (u32)f2bf(w0) | ((u32)f2bf(w1) << 16);
            *(u32*)&wlds[sr][sk] = pack;
        }
        __syncthreads();
        s16x8 af = *(const s16x8*)&wlds[mg * 16 + li][g * 8];
        s16x8 bf = *(const s16x8*)&olds[cg * 16 + li][g * 8];
        acc = __builtin_amdgcn_mfma_f32_16x16x32_bf16(af, bf, acc, 0, 0, 0);
    }
    float bias = b2[cg * 16 + li];
    float psum = 0.f;
#pragma unroll
    for (int r = 0; r < 4; r++) {
        int i = i0 + mg * 16 + g * 4 + r;
        float rsc = rsc2[(b << 11) + i];
        int c = cg * 16 + li;
        float v = acc[r] * rsc + bias;
        node[((size_t)(b << 11) + i) * NC + c] = v;
        psum += v;
    }
    // graph partial: reduce psum over g (rows) within wave, then combine mg pair.
    psum += __shfl_xor(psum, 16);
    psum += __shfl_xor(psum, 32);           // all lanes now hold column sum for li
    __shared__ float gsm[8][16];
    if (g == 0) gsm[wv][li] = psum;
    __syncthreads();
    if (t < NC) {                           // t = column c
        int c16 = t >> 4, cl = t & 15;
        gpart[(((size_t)b * (NN / 32)) + blockIdx.x) * NC + t] =
            gsm[c16 * 2][cl] + gsm[c16 * 2 + 1][cl];
    }
}

// ---- graph scores: reduce per-block partials -------------------------------
__global__ void kgraph2(const float* __restrict__ gpart, float* __restrict__ graph) {
    int b = blockIdx.x;
    int c = threadIdx.x & 63, ch = threadIdx.x >> 6;
    float s = 0.f;
    for (int p = ch; p < NN / 32; p += 4)
        s += gpart[(((size_t)b * (NN / 32)) + p) * NC + c];
    __shared__ float red[4][64];
    red[ch][c] = s;
    __syncthreads();
    if (ch == 0) graph[b * NC + c] = red[0][c] + red[1][c] + red[2][c] + red[3][c];
}

extern "C" void kernel_launch(void* const* d_in, const int* in_sizes, int n_in,
                              void* d_out, int out_size, void* d_ws, size_t ws_size,
                              hipStream_t stream) {
    const float* X   = (const float*)d_in[0];
    const float* A   = (const float*)d_in[1];
    const float* a1s = (const float*)d_in[2];
    const float* a1d = (const float*)d_in[3];
    const float* W1  = (const float*)d_in[4];
    const float* b1  = (const float*)d_in[5];
    const float* a2s = (const float*)d_in[6];
    const float* a2d = (const float*)d_in[7];
    const float* W2  = (const float*)d_in[8];
    const float* b2  = (const float*)d_in[9];

    float* node  = (float*)d_out;                 // [4][2048][64]
    float* graph = node + (size_t)NB * NN * NC;   // [4][64]

    char* w = (char*)d_ws;
    float* FS1  = (float*)w; w += NB * NN * 4;
    float* FD1  = (float*)w; w += NB * NN * 4;
    float* FS2  = (float*)w; w += NB * NN * 4;
    float* FD2  = (float*)w; w += NB * NN * 4;
    float* dvec = (float*)w; w += NB * NN * 4;
    float* rsc1 = (float*)w; w += NB * NN * 4;
    float* rsc2 = (float*)w; w += NB * NN * 4;
    u64*  bm    = (u64*)w;  w += (size_t)NB * NN * 32 * 8;    // 2 MB
    u16*  XT    = (u16*)w;  w += (size_t)NB * NF * NN * 2;    // 2 MB
    float* out1 = (float*)w; w += (size_t)NB * NN * NH * 4;   // 8 MB
    u16*  OW2T  = (u16*)w;  w += (size_t)NB * NC * NN * 2;    // 1 MB
    u16*  W1T   = (u16*)w;  w += NH * NF * 2;
    u16*  W2T   = (u16*)w;  w += NC * NH * 2;
    float* gpart = (float*)w; w += (size_t)NB * (NN / 32) * NC * 4;  // 64 KB

    kprep_w <<<192, 256, 0, stream>>>(W1, W2, W1T, W2T);
    kprep_xt<<<dim3(32, NB), 256, 0, stream>>>(X, XT);
    kdots1  <<<NB * NN / 4, 256, 0, stream>>>(X, a1s, a1d, FS1, FD1);
    kstats1 <<<NB * NN, 256, 0, stream>>>(A, FS1, FD1, dvec, rsc1, bm);
    kspmm1  <<<dim3(NN / 32, NB), 512, 0, stream>>>((const u32*)bm, FS1, FD1, dvec,
                                                    rsc1, XT, W1T, b1, out1);
    kdots2  <<<NB * NN / 4, 256, 0, stream>>>(out1, a2s, a2d, FS2, FD2);
    kstats2 <<<NB * NN / 4, 256, 0, stream>>>(bm, FS2, FD2, dvec, rsc2);
    kgemm2  <<<dim3(NN / 32, NB), 256, 0, stream>>>(out1, W2T, OW2T);
    kspmm2  <<<dim3(NN / 32, NB), 512, 0, stream>>>((const u32*)bm, FS2, FD2, dvec,
                                                    rsc2, OW2T, b2, node, gpart);
    kgraph2 <<<NB, 256, 0, stream>>>(gpart, graph);
}

// Round 3
// 102.860 us; speedup vs baseline: 2.5298x; 1.4077x over previous
//
#include <hip/hip_runtime.h>

// ---------------------------------------------------------------------------
// TwoLayerGCN on MI355X (gfx950).
// B=4, N=2048, F=128, H=256, C=64.
//
// Math restructure (exact up to fp rounding):
//   deg_i = sum_j A_ij ; d_i = rsqrt(deg_i + 1)
//   w_ij  = [A_ij>0] * exp(lrelu(fs_i + fd_j)) * d_j * (1 + [i==j])
//   rs_i  = sum_j [A_ij>0] * exp(lrelu(fs_i + fd_j))
//   layer1: out1 = relu( (d_i/rs_i) * (W @ X) @ W1 + b1 )   (fused: T=W@X, T@W1)
//   layer2: node = (d_i/rs_i) * W2mat @ (out1 @ W2) + b2
//   graph  = sum_i node   (partials fused into kspmm2; tiny reduce kernel)
// R1 fix: kgraph 4-block latency kernel (122us) -> fused partials.
// R2 fix: spmm kernels were barrier-bound (64 ksteps x 2 barriers, 2 MFMA/wave
// between barriers, MfmaUtil 3%). Now: K-step 64, ONE barrier per step,
// double-buffered LDS with loads issued pre-barrier, 8 waves (k-split halves),
// XOR bank swizzle (col ^= (row&7)<<3) on all bf16 tiles.
// ---------------------------------------------------------------------------

typedef __attribute__((ext_vector_type(8))) short  s16x8;
typedef __attribute__((ext_vector_type(4))) float  f32x4;
typedef unsigned short u16;
typedef unsigned int   u32;
typedef unsigned long long u64;

#define LOG2E 1.4426950408889634f
#define NB 4
#define NN 2048
#define NF 128
#define NH 256
#define NC 64
#define KS 64
#define NK (NN / KS)

__device__ __forceinline__ u16 f2bf(float f) {
    u32 x = __builtin_bit_cast(u32, f);
    return (u16)((x + 0x7fffu + ((x >> 16) & 1u)) >> 16);
}

// ---- prep: W1T bf16 [256][128], W2T bf16 [64][256] -------------------------
__global__ void kprep_w(const float* __restrict__ W1, const float* __restrict__ W2,
                        u16* __restrict__ W1T, u16* __restrict__ W2T) {
    int t = blockIdx.x * 256 + threadIdx.x;
    if (t < NF * NH) {                 // W1 [128][256] -> W1T [256][128]
        int k = t >> 8, c = t & 255;
        W1T[c * NF + k] = f2bf(W1[t]);
    }
    int t2 = t - NF * NH;
    if (t2 >= 0 && t2 < NH * NC) {     // W2 [256][64] -> W2T [64][256]
        int k = t2 >> 6, c = t2 & 63;
        W2T[c * NH + k] = f2bf(W2[t2]);
    }
}

// ---- prep: XT bf16 [B][128][2048] = transpose of X -------------------------
__global__ void kprep_xt(const float* __restrict__ X, u16* __restrict__ XT) {
    __shared__ float tile[64][132];
    int b = blockIdx.y, i0 = blockIdx.x * 64;
    for (int idx = threadIdx.x; idx < 64 * NF; idx += 256) {
        int r = idx >> 7, c = idx & 127;
        tile[r][c] = X[((size_t)b * NN + i0 + r) * NF + c];
    }
    __syncthreads();
    int c = threadIdx.x >> 1, half = threadIdx.x & 1;
    __attribute__((aligned(16))) u16 tmp[32];
#pragma unroll
    for (int q = 0; q < 32; q++) tmp[q] = f2bf(tile[half * 32 + q][c]);
    int4* dst = (int4*)&XT[((size_t)b * NF + c) * NN + i0 + half * 32];
    const int4* sv = (const int4*)tmp;
    dst[0] = sv[0]; dst[1] = sv[1]; dst[2] = sv[2]; dst[3] = sv[3];
}

// ---- dots layer1: FS1/FD1 = LOG2E * (X @ a_src / a_dst) --------------------
__global__ void kdots1(const float* __restrict__ X, const float* __restrict__ asrc,
                       const float* __restrict__ adst,
                       float* __restrict__ FS, float* __restrict__ FD) {
    int wv = threadIdx.x >> 6, l = threadIdx.x & 63;
    int row = blockIdx.x * 4 + wv;                    // 0..8191 (b*2048+i)
    float2 x  = *(const float2*)&X[(size_t)row * NF + l * 2];
    float2 as = *(const float2*)&asrc[l * 2];
    float2 ad = *(const float2*)&adst[l * 2];
    float s = x.x * as.x + x.y * as.y;
    float d = x.x * ad.x + x.y * ad.y;
#pragma unroll
    for (int o = 32; o > 0; o >>= 1) { s += __shfl_down(s, o); d += __shfl_down(d, o); }
    if (l == 0) { FS[row] = s * LOG2E; FD[row] = d * LOG2E; }
}

// ---- dots layer2 (256-dim from out1) ---------------------------------------
__global__ void kdots2(const float* __restrict__ out1, const float* __restrict__ asrc,
                       const float* __restrict__ adst,
                       float* __restrict__ FS, float* __restrict__ FD) {
    int wv = threadIdx.x >> 6, l = threadIdx.x & 63;
    int row = blockIdx.x * 4 + wv;
    float4 x  = *(const float4*)&out1[(size_t)row * NH + l * 4];
    float4 as = *(const float4*)&asrc[l * 4];
    float4 ad = *(const float4*)&adst[l * 4];
    float s = x.x * as.x + x.y * as.y + x.z * as.z + x.w * as.w;
    float d = x.x * ad.x + x.y * ad.y + x.z * ad.z + x.w * ad.w;
#pragma unroll
    for (int o = 32; o > 0; o >>= 1) { s += __shfl_down(s, o); d += __shfl_down(d, o); }
    if (l == 0) { FS[row] = s * LOG2E; FD[row] = d * LOG2E; }
}

// ---- stats layer1: the ONLY full read of A. deg->d, rs1->rowscale1, bitmask.
__global__ void kstats1(const float* __restrict__ A, const float* __restrict__ FS,
                        const float* __restrict__ FD,
                        float* __restrict__ dvec, float* __restrict__ rsc1,
                        u64* __restrict__ bm) {
    int row = blockIdx.x;                      // 0..8191
    int b = row >> 11;
    const float* Arow = A + (size_t)row * NN;
    const float* FDb = FD + (b << 11);
    float fs = FS[row];
    int l = threadIdx.x & 63, wv = threadIdx.x >> 6;
    float deg = 0.f, rs = 0.f;
#pragma unroll
    for (int e = 0; e < 8; e++) {
        int j = e * 256 + threadIdx.x;         // wave-consecutive j for ballot
        float a = Arow[j];
        float s = fs + FDb[j];
        deg += a;
        bool nb = a > 0.f;
        float w = exp2f(fmaxf(s, 0.2f * s));
        rs += nb ? w : 0.f;
        u64 m = __ballot(nb);
        if (l == 0) bm[(size_t)row * 32 + e * 4 + wv] = m;
    }
    __shared__ float red[2][4];
#pragma unroll
    for (int o = 32; o > 0; o >>= 1) { deg += __shfl_down(deg, o); rs += __shfl_down(rs, o); }
    if (l == 0) { red[0][wv] = deg; red[1][wv] = rs; }
    __syncthreads();
    if (threadIdx.x == 0) {
        float D = red[0][0] + red[0][1] + red[0][2] + red[0][3];
        float R = red[1][0] + red[1][1] + red[1][2] + red[1][3];
        float dv = rsqrtf(D + 1.0f);
        dvec[row] = dv;
        rsc1[row] = dv / R;
    }
}

// ---- stats layer2: rs2 from bitmask ----------------------------------------
__global__ void kstats2(const u64* __restrict__ bm, const float* __restrict__ FS,
                        const float* __restrict__ FD, const float* __restrict__ dvec,
                        float* __restrict__ rsc2) {
    int wv = threadIdx.x >> 6, l = threadIdx.x & 63;
    int row = blockIdx.x * 4 + wv;
    int b = row >> 11;
    const float* FDb = FD + (b << 11);
    float fs = FS[row], rs = 0.f;
    for (int e = 0; e < 32; e++) {
        u64 m = bm[(size_t)row * 32 + e];
        float fd = FDb[e * 64 + l];
        float s = fs + fd;
        float w = exp2f(fmaxf(s, 0.2f * s));
        rs += ((m >> l) & 1ull) ? w : 0.f;
    }
#pragma unroll
    for (int o = 32; o > 0; o >>= 1) rs += __shfl_down(rs, o);
    if (l == 0) rsc2[row] = dvec[row] / rs;
}

// ---- fused layer1 spmm: out1 = relu(rowscale * (W@X)@W1 + b1) --------------
// 512 thr (8 waves): stage1 waves = (kf = wv>>2 k-half, cf = wv&3 col group).
// One barrier per 64-wide K-step; double-buffered swizzled LDS.
__global__ __launch_bounds__(512) void kspmm1(
    const u32* __restrict__ bm32, const float* __restrict__ FS,
    const float* __restrict__ FD, const float* __restrict__ dvec,
    const float* __restrict__ rsc1, const u16* __restrict__ XT,
    const u16* __restrict__ W1T, const float* __restrict__ b1,
    float* __restrict__ out1) {
    const int b = blockIdx.y;
    const int i0 = blockIdx.x * 32;
    const int t = threadIdx.x;
    const int l = t & 63, wv = t >> 6;
    const int g = l >> 4, li = l & 15;
    const int kf = wv >> 2;          // k-half within step
    const int cf = wv & 3;           // 32-col group of X features

    __shared__ __attribute__((aligned(16))) u16 xb[2][128][64];
    __shared__ __attribute__((aligned(16))) u16 wb[2][32][64];
    __shared__ __attribute__((aligned(16))) float tlds[32][132];

    // staging maps
    const int xr = t >> 2;                 // X feature row 0..127
    const int xc = (t & 3) * 16;           // u16 col base (2 chunks: +0, +8)
    const int wr = t & 31;                 // weight row
    const int wc = (t >> 5) * 4;           // 4 weight cols

    const int grow = i0 + wr;
    const float fs_r = FS[(b << 11) + grow];
    const float* FDb = FD + (b << 11);
    const float* Db  = dvec + (b << 11);
    const u32* bmrow = bm32 + ((size_t)((b << 11) + grow)) * 64;
    const u16* XTb = XT + (size_t)b * NF * NN;

    int4 xv0, xv1; float4 fdv, djv; u32 wbits; int jj;

#define LOADS1(K0_) { \
    const u16* xp = XTb + (size_t)xr * NN + (K0_) + xc; \
    xv0 = *(const int4*)xp; xv1 = *(const int4*)(xp + 8); \
    fdv = *(const float4*)&FDb[(K0_) + wc]; \
    djv = *(const float4*)&Db[(K0_) + wc]; \
    wbits = bmrow[((K0_) + wc) >> 5] >> (wc & 31); \
    jj = (K0_) + wc; }

#define WRITEB1(BI_) { \
    const int sw = (xr & 7) << 3; \
    *(int4*)&xb[BI_][xr][xc ^ sw] = xv0; \
    *(int4*)&xb[BI_][xr][(xc + 8) ^ sw] = xv1; \
    float fdq[4] = {fdv.x, fdv.y, fdv.z, fdv.w}; \
    float djq[4] = {djv.x, djv.y, djv.z, djv.w}; \
    u16 wq[4]; \
    _Pragma("unroll") \
    for (int q = 0; q < 4; q++) { \
        float s_ = fs_r + fdq[q]; \
        float w_ = exp2f(fmaxf(s_, 0.2f * s_)) * djq[q]; \
        if (jj + q == grow) w_ *= 2.f; \
        wq[q] = ((wbits >> q) & 1u) ? f2bf(w_) : (u16)0; } \
    uint2 pk; \
    pk.x = (u32)wq[0] | ((u32)wq[1] << 16); \
    pk.y = (u32)wq[2] | ((u32)wq[3] << 16); \
    *(uint2*)&wb[BI_][wr][wc ^ ((wr & 7) << 3)] = pk; }

    f32x4 zero = {0.f, 0.f, 0.f, 0.f};
    f32x4 acc00 = zero, acc01 = zero, acc10 = zero, acc11 = zero;

    LOADS1(0); WRITEB1(0);
    for (int k = 0; k < NK; ++k) {
        const int nxt = k + 1;
        if (nxt < NK) LOADS1(nxt * KS);
        __syncthreads();
        const int cb = k & 1;
        const int kc = kf * 32 + g * 8;
        const int swr = (li & 7) << 3;
        s16x8 af0 = *(const s16x8*)&wb[cb][li]          [kc ^ swr];
        s16x8 af1 = *(const s16x8*)&wb[cb][16 + li]     [kc ^ swr];
        s16x8 bf0 = *(const s16x8*)&xb[cb][cf * 32 + li][kc ^ swr];
        s16x8 bf1 = *(const s16x8*)&xb[cb][cf * 32 + 16 + li][kc ^ swr];
        acc00 = __builtin_amdgcn_mfma_f32_16x16x32_bf16(af0, bf0, acc00, 0, 0, 0);
        acc01 = __builtin_amdgcn_mfma_f32_16x16x32_bf16(af0, bf1, acc01, 0, 0, 0);
        acc10 = __builtin_amdgcn_mfma_f32_16x16x32_bf16(af1, bf0, acc10, 0, 0, 0);
        acc11 = __builtin_amdgcn_mfma_f32_16x16x32_bf16(af1, bf1, acc11, 0, 0, 0);
        if (nxt < NK) WRITEB1(nxt & 1);
    }
    __syncthreads();
    // combine k-halves into tlds (f32)
    if (wv < 4) {
#pragma unroll
        for (int r = 0; r < 4; r++) {
            tlds[g * 4 + r]     [cf * 32 + li]      = acc00[r];
            tlds[g * 4 + r]     [cf * 32 + 16 + li] = acc01[r];
            tlds[16 + g * 4 + r][cf * 32 + li]      = acc10[r];
            tlds[16 + g * 4 + r][cf * 32 + 16 + li] = acc11[r];
        }
    }
    __syncthreads();
    if (wv >= 4) {
#pragma unroll
        for (int r = 0; r < 4; r++) {
            tlds[g * 4 + r]     [cf * 32 + li]      += acc00[r];
            tlds[g * 4 + r]     [cf * 32 + 16 + li] += acc01[r];
            tlds[16 + g * 4 + r][cf * 32 + li]      += acc10[r];
            tlds[16 + g * 4 + r][cf * 32 + 16 + li] += acc11[r];
        }
    }
    __syncthreads();
    // stage 2: out1_block[32][256] = T[32][128] @ W1[128][256]; wave = 32 cols
    const int c0 = wv * 32;
    f32x4 p00 = zero, p01 = zero, p10 = zero, p11 = zero;
    for (int k2 = 0; k2 < 4; ++k2) {
        s16x8 a2[2];
#pragma unroll
        for (int mt = 0; mt < 2; ++mt) {
            const float* tp = &tlds[mt * 16 + li][k2 * 32 + g * 8];
            float4 t0 = *(const float4*)tp;
            float4 t1 = *(const float4*)(tp + 4);
            s16x8 aa;
            aa[0] = (short)f2bf(t0.x); aa[1] = (short)f2bf(t0.y);
            aa[2] = (short)f2bf(t0.z); aa[3] = (short)f2bf(t0.w);
            aa[4] = (short)f2bf(t1.x); aa[5] = (short)f2bf(t1.y);
            aa[6] = (short)f2bf(t1.z); aa[7] = (short)f2bf(t1.w);
            a2[mt] = aa;
        }
        s16x8 w0 = *(const s16x8*)&W1T[(size_t)(c0 + li) * NF + k2 * 32 + g * 8];
        s16x8 w1 = *(const s16x8*)&W1T[(size_t)(c0 + 16 + li) * NF + k2 * 32 + g * 8];
        p00 = __builtin_amdgcn_mfma_f32_16x16x32_bf16(a2[0], w0, p00, 0, 0, 0);
        p01 = __builtin_amdgcn_mfma_f32_16x16x32_bf16(a2[0], w1, p01, 0, 0, 0);
        p10 = __builtin_amdgcn_mfma_f32_16x16x32_bf16(a2[1], w0, p10, 0, 0, 0);
        p11 = __builtin_amdgcn_mfma_f32_16x16x32_bf16(a2[1], w1, p11, 0, 0, 0);
    }
#pragma unroll
    for (int mt = 0; mt < 2; ++mt) {
        f32x4 pa = mt ? p10 : p00;
        f32x4 pb = mt ? p11 : p01;
#pragma unroll
        for (int r = 0; r < 4; r++) {
            int i = i0 + mt * 16 + g * 4 + r;
            float rsc = rsc1[(b << 11) + i];
            int ca = c0 + li, cb2 = c0 + 16 + li;
            float va = pa[r] * rsc + b1[ca];
            float vb = pb[r] * rsc + b1[cb2];
            out1[((size_t)(b << 11) + i) * NH + ca]  = fmaxf(va, 0.f);
            out1[((size_t)(b << 11) + i) * NH + cb2] = fmaxf(vb, 0.f);
        }
    }
#undef LOADS1
#undef WRITEB1
}

// ---- gemm2: OW2T bf16 [B][64][2048] = (out1 @ W2)^T ------------------------
__global__ __launch_bounds__(256) void kgemm2(const float* __restrict__ out1,
                                              const u16* __restrict__ W2T,
                                              u16* __restrict__ OW2T) {
    const int b = blockIdx.y;
    const int j0 = blockIdx.x * 32;
    const int t = threadIdx.x;
    const int l = t & 63, wv = t >> 6;
    const int g = l >> 4, li = l & 15;
    const int mt = wv & 1, cg = wv >> 1;      // 2 row tiles x 2 col groups(32)
    f32x4 zero = {0.f, 0.f, 0.f, 0.f};
    f32x4 acc[2] = {zero, zero};
    for (int k0 = 0; k0 < NH; k0 += 32) {
        const float* src = out1 + ((size_t)(b << 11) + j0 + mt * 16 + li) * NH + k0 + g * 8;
        float4 v0 = *(const float4*)src;
        float4 v1 = *(const float4*)(src + 4);
        s16x8 af;
        af[0] = (short)f2bf(v0.x); af[1] = (short)f2bf(v0.y);
        af[2] = (short)f2bf(v0.z); af[3] = (short)f2bf(v0.w);
        af[4] = (short)f2bf(v1.x); af[5] = (short)f2bf(v1.y);
        af[6] = (short)f2bf(v1.z); af[7] = (short)f2bf(v1.w);
#pragma unroll
        for (int nf = 0; nf < 2; nf++) {
            s16x8 bf = *(const s16x8*)&W2T[(size_t)(cg * 32 + nf * 16 + li) * NH + k0 + g * 8];
            acc[nf] = __builtin_amdgcn_mfma_f32_16x16x32_bf16(af, bf, acc[nf], 0, 0, 0);
        }
    }
#pragma unroll
    for (int nf = 0; nf < 2; nf++) {
        int c = cg * 32 + nf * 16 + li;
        uint2 pk;
        pk.x = (u32)f2bf(acc[nf][0]) | ((u32)f2bf(acc[nf][1]) << 16);
        pk.y = (u32)f2bf(acc[nf][2]) | ((u32)f2bf(acc[nf][3]) << 16);
        *(uint2*)&OW2T[((size_t)b * NC + c) * NN + j0 + mt * 16 + g * 4] = pk;
    }
}

// ---- layer2 spmm: node = rowscale2 * W2mat @ OW2 + b2; graph partials ------
// Same pipeline as kspmm1: 512 thr, kf = wv>>2, cf = wv&3 (16-col group).
__global__ __launch_bounds__(512) void kspmm2(
    const u32* __restrict__ bm32, const float* __restrict__ FS,
    const float* __restrict__ FD, const float* __restrict__ dvec,
    const float* __restrict__ rsc2, const u16* __restrict__ OW2T,
    const float* __restrict__ b2, float* __restrict__ node,
    float* __restrict__ gpart) {
    const int b = blockIdx.y;
    const int i0 = blockIdx.x * 32;
    const int t = threadIdx.x;
    const int l = t & 63, wv = t >> 6;
    const int g = l >> 4, li = l & 15;
    const int kf = wv >> 2;
    const int cf = wv & 3;

    __shared__ __attribute__((aligned(16))) u16 ob[2][64][64];
    __shared__ __attribute__((aligned(16))) u16 wb2[2][32][64];
    __shared__ __attribute__((aligned(16))) float tl2[32][68];

    const int orow = t >> 3;               // 0..63
    const int oseg = (t & 7) * 8;          // u16 col base
    const int wr = t & 31;
    const int wc = (t >> 5) * 4;

    const int grow = i0 + wr;
    const float fs_r = FS[(b << 11) + grow];
    const float* FDb = FD + (b << 11);
    const float* Db  = dvec + (b << 11);
    const u32* bmrow = bm32 + ((size_t)((b << 11) + grow)) * 64;
    const u16* Ob = OW2T + (size_t)b * NC * NN;

    int4 ov; float4 fdv, djv; u32 wbits; int jj;

#define LOADS2(K0_) { \
    ov = *(const int4*)(Ob + (size_t)orow * NN + (K0_) + oseg); \
    fdv = *(const float4*)&FDb[(K0_) + wc]; \
    djv = *(const float4*)&Db[(K0_) + wc]; \
    wbits = bmrow[((K0_) + wc) >> 5] >> (wc & 31); \
    jj = (K0_) + wc; }

#define WRITEB2(BI_) { \
    *(int4*)&ob[BI_][orow][oseg ^ ((orow & 7) << 3)] = ov; \
    float fdq[4] = {fdv.x, fdv.y, fdv.z, fdv.w}; \
    float djq[4] = {djv.x, djv.y, djv.z, djv.w}; \
    u16 wq[4]; \
    _Pragma("unroll") \
    for (int q = 0; q < 4; q++) { \
        float s_ = fs_r + fdq[q]; \
        float w_ = exp2f(fmaxf(s_, 0.2f * s_)) * djq[q]; \
        if (jj + q == grow) w_ *= 2.f; \
        wq[q] = ((wbits >> q) & 1u) ? f2bf(w_) : (u16)0; } \
    uint2 pk; \
    pk.x = (u32)wq[0] | ((u32)wq[1] << 16); \
    pk.y = (u32)wq[2] | ((u32)wq[3] << 16); \
    *(uint2*)&wb2[BI_][wr][wc ^ ((wr & 7) << 3)] = pk; }

    f32x4 zero = {0.f, 0.f, 0.f, 0.f};
    f32x4 acc0 = zero, acc1 = zero;

    LOADS2(0); WRITEB2(0);
    for (int k = 0; k < NK; ++k) {
        const int nxt = k + 1;
        if (nxt < NK) LOADS2(nxt * KS);
        __syncthreads();
        const int cb = k & 1;
        const int kc = kf * 32 + g * 8;
        const int swr = (li & 7) << 3;
        s16x8 af0 = *(const s16x8*)&wb2[cb][li]     [kc ^ swr];
        s16x8 af1 = *(const s16x8*)&wb2[cb][16 + li][kc ^ swr];
        s16x8 bfr = *(const s16x8*)&ob[cb][cf * 16 + li][kc ^ swr];
        acc0 = __builtin_amdgcn_mfma_f32_16x16x32_bf16(af0, bfr, acc0, 0, 0, 0);
        acc1 = __builtin_amdgcn_mfma_f32_16x16x32_bf16(af1, bfr, acc1, 0, 0, 0);
        if (nxt < NK) WRITEB2(nxt & 1);
    }
    __syncthreads();
    if (wv < 4) {
#pragma unroll
        for (int r = 0; r < 4; r++) {
            tl2[g * 4 + r]     [cf * 16 + li] = acc0[r];
            tl2[16 + g * 4 + r][cf * 16 + li] = acc1[r];
        }
    }
    __syncthreads();
    if (wv >= 4) {
#pragma unroll
        for (int r = 0; r < 4; r++) {
            tl2[g * 4 + r]     [cf * 16 + li] += acc0[r];
            tl2[16 + g * 4 + r][cf * 16 + li] += acc1[r];
        }
    }
    __syncthreads();
    // scale + bias, store node, write back for graph partial
    {
        int r = t >> 4, c0 = (t & 15) * 4;
        float rsc = rsc2[(b << 11) + i0 + r];
        float4 v = *(const float4*)&tl2[r][c0];
        float4 bb = *(const float4*)&b2[c0];
        v.x = v.x * rsc + bb.x; v.y = v.y * rsc + bb.y;
        v.z = v.z * rsc + bb.z; v.w = v.w * rsc + bb.w;
        *(float4*)&node[((size_t)(b << 11) + i0 + r) * NC + c0] = v;
        *(float4*)&tl2[r][c0] = v;
    }
    __syncthreads();
    if (t < NC) {
        float s = 0.f;
#pragma unroll
        for (int r = 0; r < 32; ++r) s += tl2[r][t];
        gpart[(((size_t)b * (NN / 32)) + blockIdx.x) * NC + t] = s;
    }
#undef LOADS2
#undef WRITEB2
}

// ---- graph scores: reduce per-block partials -------------------------------
__global__ void kgraph2(const float* __restrict__ gpart, float* __restrict__ graph) {
    int b = blockIdx.x;
    int c = threadIdx.x & 63, ch = threadIdx.x >> 6;
    float s = 0.f;
    for (int p = ch; p < NN / 32; p += 4)
        s += gpart[(((size_t)b * (NN / 32)) + p) * NC + c];
    __shared__ float red[4][64];
    red[ch][c] = s;
    __syncthreads();
    if (ch == 0) graph[b * NC + c] = red[0][c] + red[1][c] + red[2][c] + red[3][c];
}

extern "C" void kernel_launch(void* const* d_in, const int* in_sizes, int n_in,
                              void* d_out, int out_size, void* d_ws, size_t ws_size,
                              hipStream_t stream) {
    const float* X   = (const float*)d_in[0];
    const float* A   = (const float*)d_in[1];
    const float* a1s = (const float*)d_in[2];
    const float* a1d = (const float*)d_in[3];
    const float* W1  = (const float*)d_in[4];
    const float* b1  = (const float*)d_in[5];
    const float* a2s = (const float*)d_in[6];
    const float* a2d = (const float*)d_in[7];
    const float* W2  = (const float*)d_in[8];
    const float* b2  = (const float*)d_in[9];

    float* node  = (float*)d_out;                 // [4][2048][64]
    float* graph = node + (size_t)NB * NN * NC;   // [4][64]

    char* w = (char*)d_ws;
    float* FS1  = (float*)w; w += NB * NN * 4;
    float* FD1  = (float*)w; w += NB * NN * 4;
    float* FS2  = (float*)w; w += NB * NN * 4;
    float* FD2  = (float*)w; w += NB * NN * 4;
    float* dvec = (float*)w; w += NB * NN * 4;
    float* rsc1 = (float*)w; w += NB * NN * 4;
    float* rsc2 = (float*)w; w += NB * NN * 4;
    u64*  bm    = (u64*)w;  w += (size_t)NB * NN * 32 * 8;    // 2 MB
    u16*  XT    = (u16*)w;  w += (size_t)NB * NF * NN * 2;    // 2 MB
    float* out1 = (float*)w; w += (size_t)NB * NN * NH * 4;   // 8 MB
    u16*  OW2T  = (u16*)w;  w += (size_t)NB * NC * NN * 2;    // 1 MB
    u16*  W1T   = (u16*)w;  w += NH * NF * 2;
    u16*  W2T   = (u16*)w;  w += NC * NH * 2;
    float* gpart = (float*)w; w += (size_t)NB * (NN / 32) * NC * 4;  // 64 KB

    kprep_w <<<192, 256, 0, stream>>>(W1, W2, W1T, W2T);
    kprep_xt<<<dim3(32, NB), 256, 0, stream>>>(X, XT);
    kdots1  <<<NB * NN / 4, 256, 0, stream>>>(X, a1s, a1d, FS1, FD1);
    kstats1 <<<NB * NN, 256, 0, stream>>>(A, FS1, FD1, dvec, rsc1, bm);
    kspmm1  <<<dim3(NN / 32, NB), 512, 0, stream>>>((const u32*)bm, FS1, FD1, dvec,
                                                    rsc1, XT, W1T, b1, out1);
    kdots2  <<<NB * NN / 4, 256, 0, stream>>>(out1, a2s, a2d, FS2, FD2);
    kstats2 <<<NB * NN / 4, 256, 0, stream>>>(bm, FS2, FD2, dvec, rsc2);
    kgemm2  <<<dim3(NN / 32, NB), 256, 0, stream>>>(out1, W2T, OW2T);
    kspmm2  <<<dim3(NN / 32, NB), 512, 0, stream>>>((const u32*)bm, FS2, FD2, dvec,
                                                    rsc2, OW2T, b2, node, gpart);
    kgraph2 <<<NB, 256, 0, stream>>>(gpart, graph);
}

// Round 4
// 90.453 us; speedup vs baseline: 2.8768x; 1.1372x over previous
//
#include <hip/hip_runtime.h>

// ---------------------------------------------------------------------------
// TwoLayerGCN on MI355X (gfx950).  B=4, N=2048, F=128, H=256, C=64.
//
//   deg_i = sum_j A_ij ; d_i = rsqrt(deg_i + 1)
//   w_ij  = [A_ij>0] * exp(lrelu(fs_i + fd_j)) * d_j * (1 + [i==j])
//   rs_i  = sum_j [A_ij>0] * exp(lrelu(fs_i + fd_j))
//   layer1: out1 = relu( (d_i/rs_i) * (W @ X) @ W1 + b1 )
//   layer2: node = (d_i/rs_i) * W2mat @ (out1 @ W2) + b2 ; graph = sum_i node
//
// R1: fused graph partials (kgraph was 122us latency-bound).
// R2: SpMMs -> 1-barrier/64-wide-K-step double-buffered pipeline, XOR swizzle.
// R3: kernel-count 10 -> 5 (wall had ~40us of launch/serialization):
//   - kprep = W-prep + X-transpose + layer1 dots (same X tile).
//   - kspmm1 epilogue: out1 block stays in LDS; computes FS2/FD2 (kdots2 gone)
//     and OW2T = (out1@W2)^T (kgemm2 gone). out1 never touches HBM (-24MB).
//   - rs_i accumulated during SpMM staging (exp2 already computed there):
//     kstats2 gone, kstats1 reduced to deg+bitmask only.
// ---------------------------------------------------------------------------

typedef __attribute__((ext_vector_type(8))) short  s16x8;
typedef __attribute__((ext_vector_type(4))) float  f32x4;
typedef unsigned short u16;
typedef unsigned int   u32;
typedef unsigned long long u64;

#define LOG2E 1.4426950408889634f
#define NB 4
#define NN 2048
#define NF 128
#define NH 256
#define NC 64
#define KS 64
#define NK (NN / KS)

__device__ __forceinline__ u16 f2bf(float f) {
    u32 x = __builtin_bit_cast(u32, f);
    return (u16)((x + 0x7fffu + ((x >> 16) & 1u)) >> 16);
}

// ---- prep: W1T/W2T bf16 transposes + XT bf16 transpose + layer1 dots -------
__global__ void kprep(const float* __restrict__ X, const float* __restrict__ a1s,
                      const float* __restrict__ a1d, const float* __restrict__ W1,
                      const float* __restrict__ W2, u16* __restrict__ XT,
                      u16* __restrict__ W1T, u16* __restrict__ W2T,
                      float* __restrict__ FS1, float* __restrict__ FD1) {
    if (blockIdx.x == 32) {               // weight prep, split over 4 y-blocks
        int t = blockIdx.y * 256 + threadIdx.x;
        for (int i = t; i < NF * NH; i += 1024) {
            int k = i >> 8, c = i & 255;
            W1T[c * NF + k] = f2bf(W1[i]);
        }
        for (int i = t; i < NH * NC; i += 1024) {
            int k = i >> 6, c = i & 63;
            W2T[c * NH + k] = f2bf(W2[i]);
        }
        return;
    }
    __shared__ float tile[64][132];
    __shared__ float asb[NF], adb[NF];
    __shared__ float dred[64][4][2];
    int b = blockIdx.y, i0 = blockIdx.x * 64;
    if (threadIdx.x < 128) asb[threadIdx.x] = a1s[threadIdx.x];
    else                   adb[threadIdx.x - 128] = a1d[threadIdx.x - 128];
    for (int idx = threadIdx.x; idx < 64 * NF; idx += 256) {
        int r = idx >> 7, c = idx & 127;
        tile[r][c] = X[((size_t)b * NN + i0 + r) * NF + c];
    }
    __syncthreads();
    {   // layer1 dots: 64 rows x 4 col-chunks of 32
        int r = threadIdx.x & 63, ch = threadIdx.x >> 6;
        float ps = 0.f, pd = 0.f;
#pragma unroll
        for (int q = 0; q < 32; q++) {
            float x = tile[r][ch * 32 + q];
            ps += x * asb[ch * 32 + q];
            pd += x * adb[ch * 32 + q];
        }
        dred[r][ch][0] = ps; dred[r][ch][1] = pd;
    }
    {   // XT transpose
        int c = threadIdx.x >> 1, half = threadIdx.x & 1;
        __attribute__((aligned(16))) u16 tmp[32];
#pragma unroll
        for (int q = 0; q < 32; q++) tmp[q] = f2bf(tile[half * 32 + q][c]);
        int4* dst = (int4*)&XT[((size_t)b * NF + c) * NN + i0 + half * 32];
        const int4* sv = (const int4*)tmp;
        dst[0] = sv[0]; dst[1] = sv[1]; dst[2] = sv[2]; dst[3] = sv[3];
    }
    __syncthreads();
    if (threadIdx.x < 128) {
        int r = threadIdx.x & 63, which = threadIdx.x >> 6;
        float s = dred[r][0][which] + dred[r][1][which] +
                  dred[r][2][which] + dred[r][3][which];
        if (which == 0) FS1[(b << 11) + i0 + r] = s * LOG2E;
        else            FD1[(b << 11) + i0 + r] = s * LOG2E;
    }
}

// ---- stats1: the ONLY full read of A. deg -> dvec, adjacency bitmask. ------
__global__ void kstats1(const float* __restrict__ A,
                        float* __restrict__ dvec, u64* __restrict__ bm) {
    int row = blockIdx.x;                      // 0..8191
    const float* Arow = A + (size_t)row * NN;
    int l = threadIdx.x & 63, wv = threadIdx.x >> 6;
    float deg = 0.f;
#pragma unroll
    for (int e = 0; e < 8; e++) {
        int j = e * 256 + threadIdx.x;
        float a = Arow[j];
        deg += a;
        u64 m = __ballot(a > 0.f);
        if (l == 0) bm[(size_t)row * 32 + e * 4 + wv] = m;
    }
    __shared__ float red[4];
#pragma unroll
    for (int o = 32; o > 0; o >>= 1) deg += __shfl_down(deg, o);
    if (l == 0) red[wv] = deg;
    __syncthreads();
    if (threadIdx.x == 0)
        dvec[row] = rsqrtf(red[0] + red[1] + red[2] + red[3] + 1.0f);
}

// ---- fused layer1: out1(LDS) = relu(rsc*(W@X)@W1+b1); FS2/FD2; OW2T --------
__global__ __launch_bounds__(512) void kspmm1(
    const u32* __restrict__ bm32, const float* __restrict__ FS,
    const float* __restrict__ FD, const float* __restrict__ dvec,
    const u16* __restrict__ XT, const u16* __restrict__ W1T,
    const u16* __restrict__ W2T, const float* __restrict__ b1,
    const float* __restrict__ a2s, const float* __restrict__ a2d,
    float* __restrict__ FS2, float* __restrict__ FD2,
    u16* __restrict__ OW2T) {
    const int b = blockIdx.y;
    const int i0 = blockIdx.x * 32;
    const int t = threadIdx.x;
    const int l = t & 63, wv = t >> 6;
    const int g = l >> 4, li = l & 15;
    const int kf = wv >> 2;          // k-half within step
    const int cf = wv & 3;           // 32-col group of X features

    // union region: main loop {xb 32KB | wb 8KB}; epilogue {o1 33.3KB | dred 4KB}
    __shared__ __attribute__((aligned(16))) char usmem[40960];
    u16 (*xb)[64] = (u16(*)[64])usmem;             // [2*128][64]
    u16 (*wb)[64] = (u16(*)[64])(usmem + 32768);   // [2*32][64]
    float* o1   = (float*)usmem;                   // [32][260]
    float* dred = (float*)(usmem + 33280);         // [32][16][2]
    __shared__ __attribute__((aligned(16))) float tlds[32][132];
    __shared__ float rsred[16][32];
    __shared__ float rscl[32];

    const int xr = t >> 2;                 // X feature row 0..127
    const int xc = (t & 3) * 16;           // u16 col base
    const int wr = t & 31;                 // weight row
    const int wc = (t >> 5) * 4;           // 4 weight cols

    const int grow = i0 + wr;
    const float fs_r = FS[(b << 11) + grow];
    const float* FDb = FD + (b << 11);
    const float* Db  = dvec + (b << 11);
    const u32* bmrow = bm32 + ((size_t)((b << 11) + grow)) * 64;
    const u16* XTb = XT + (size_t)b * NF * NN;

    int4 xv0, xv1; float4 fdv, djv; u32 wbits; int jj;
    float rs_acc = 0.f;

#define LOADS1(K0_) { \
    const u16* xp = XTb + (size_t)xr * NN + (K0_) + xc; \
    xv0 = *(const int4*)xp; xv1 = *(const int4*)(xp + 8); \
    fdv = *(const float4*)&FDb[(K0_) + wc]; \
    djv = *(const float4*)&Db[(K0_) + wc]; \
    wbits = bmrow[((K0_) + wc) >> 5] >> (wc & 31); \
    jj = (K0_) + wc; }

#define WRITEB1(BI_) { \
    const int sw = (xr & 7) << 3; \
    *(int4*)&xb[(BI_) * 128 + xr][xc ^ sw] = xv0; \
    *(int4*)&xb[(BI_) * 128 + xr][(xc + 8) ^ sw] = xv1; \
    float fdq[4] = {fdv.x, fdv.y, fdv.z, fdv.w}; \
    float djq[4] = {djv.x, djv.y, djv.z, djv.w}; \
    u16 wq[4]; \
    _Pragma("unroll") \
    for (int q = 0; q < 4; q++) { \
        float s_ = fs_r + fdq[q]; \
        float e_ = exp2f(fmaxf(s_, 0.2f * s_)); \
        rs_acc += ((wbits >> q) & 1u) ? e_ : 0.f; \
        float w_ = e_ * djq[q]; \
        if (jj + q == grow) w_ *= 2.f; \
        wq[q] = ((wbits >> q) & 1u) ? f2bf(w_) : (u16)0; } \
    uint2 pk; \
    pk.x = (u32)wq[0] | ((u32)wq[1] << 16); \
    pk.y = (u32)wq[2] | ((u32)wq[3] << 16); \
    *(uint2*)&wb[(BI_) * 32 + wr][wc ^ ((wr & 7) << 3)] = pk; }

    f32x4 zero = {0.f, 0.f, 0.f, 0.f};
    f32x4 acc00 = zero, acc01 = zero, acc10 = zero, acc11 = zero;

    LOADS1(0); WRITEB1(0);
    for (int k = 0; k < NK; ++k) {
        const int nxt = k + 1;
        if (nxt < NK) LOADS1(nxt * KS);
        __syncthreads();
        const int cb = k & 1;
        const int kc = kf * 32 + g * 8;
        const int swr = (li & 7) << 3;
        s16x8 af0 = *(const s16x8*)&wb[cb * 32 + li]          [kc ^ swr];
        s16x8 af1 = *(const s16x8*)&wb[cb * 32 + 16 + li]     [kc ^ swr];
        s16x8 bf0 = *(const s16x8*)&xb[cb * 128 + cf * 32 + li][kc ^ swr];
        s16x8 bf1 = *(const s16x8*)&xb[cb * 128 + cf * 32 + 16 + li][kc ^ swr];
        acc00 = __builtin_amdgcn_mfma_f32_16x16x32_bf16(af0, bf0, acc00, 0, 0, 0);
        acc01 = __builtin_amdgcn_mfma_f32_16x16x32_bf16(af0, bf1, acc01, 0, 0, 0);
        acc10 = __builtin_amdgcn_mfma_f32_16x16x32_bf16(af1, bf0, acc10, 0, 0, 0);
        acc11 = __builtin_amdgcn_mfma_f32_16x16x32_bf16(af1, bf1, acc11, 0, 0, 0);
        if (nxt < NK) WRITEB1(nxt & 1);
    }
    rsred[t >> 5][wr] = rs_acc;
    __syncthreads();
    if (t < 32) {               // rowscale1 = d_i / rs_i
        float rs = 0.f;
#pragma unroll
        for (int s = 0; s < 16; ++s) rs += rsred[s][t];
        rscl[t] = Db[i0 + t] / rs;
    }
    // combine k-halves into tlds (f32)
    if (wv < 4) {
#pragma unroll
        for (int r = 0; r < 4; r++) {
            tlds[g * 4 + r]     [cf * 32 + li]      = acc00[r];
            tlds[g * 4 + r]     [cf * 32 + 16 + li] = acc01[r];
            tlds[16 + g * 4 + r][cf * 32 + li]      = acc10[r];
            tlds[16 + g * 4 + r][cf * 32 + 16 + li] = acc11[r];
        }
    }
    __syncthreads();
    if (wv >= 4) {
#pragma unroll
        for (int r = 0; r < 4; r++) {
            tlds[g * 4 + r]     [cf * 32 + li]      += acc00[r];
            tlds[g * 4 + r]     [cf * 32 + 16 + li] += acc01[r];
            tlds[16 + g * 4 + r][cf * 32 + li]      += acc10[r];
            tlds[16 + g * 4 + r][cf * 32 + 16 + li] += acc11[r];
        }
    }
    __syncthreads();
    // stage 2: out1_block[32][256] = T[32][128] @ W1[128][256]; wave = 32 cols
    const int c0 = wv * 32;
    f32x4 p00 = zero, p01 = zero, p10 = zero, p11 = zero;
    for (int k2 = 0; k2 < 4; ++k2) {
        s16x8 a2f[2];
#pragma unroll
        for (int mt = 0; mt < 2; ++mt) {
            const float* tp = &tlds[mt * 16 + li][k2 * 32 + g * 8];
            float4 t0 = *(const float4*)tp;
            float4 t1 = *(const float4*)(tp + 4);
            s16x8 aa;
            aa[0] = (short)f2bf(t0.x); aa[1] = (short)f2bf(t0.y);
            aa[2] = (short)f2bf(t0.z); aa[3] = (short)f2bf(t0.w);
            aa[4] = (short)f2bf(t1.x); aa[5] = (short)f2bf(t1.y);
            aa[6] = (short)f2bf(t1.z); aa[7] = (short)f2bf(t1.w);
            a2f[mt] = aa;
        }
        s16x8 w0 = *(const s16x8*)&W1T[(size_t)(c0 + li) * NF + k2 * 32 + g * 8];
        s16x8 w1 = *(const s16x8*)&W1T[(size_t)(c0 + 16 + li) * NF + k2 * 32 + g * 8];
        p00 = __builtin_amdgcn_mfma_f32_16x16x32_bf16(a2f[0], w0, p00, 0, 0, 0);
        p01 = __builtin_amdgcn_mfma_f32_16x16x32_bf16(a2f[0], w1, p01, 0, 0, 0);
        p10 = __builtin_amdgcn_mfma_f32_16x16x32_bf16(a2f[1], w0, p10, 0, 0, 0);
        p11 = __builtin_amdgcn_mfma_f32_16x16x32_bf16(a2f[1], w1, p11, 0, 0, 0);
    }
    __syncthreads();   // xb/wb dead; rscl visible; o1 region free
    // out1 block -> LDS o1[32][260] with relu(scale+bias)
#pragma unroll
    for (int mt = 0; mt < 2; ++mt) {
        f32x4 pa = mt ? p10 : p00;
        f32x4 pb = mt ? p11 : p01;
#pragma unroll
        for (int r = 0; r < 4; r++) {
            int rr = mt * 16 + g * 4 + r;
            float rsc = rscl[rr];
            int ca = c0 + li, cb2 = c0 + 16 + li;
            o1[rr * 260 + ca]  = fmaxf(pa[r] * rsc + b1[ca], 0.f);
            o1[rr * 260 + cb2] = fmaxf(pb[r] * rsc + b1[cb2], 0.f);
        }
    }
    __syncthreads();
    // layer-2 dots: 32 rows x 16 segs of 16 cols
    {
        int r = t >> 4, seg = t & 15;
        float ps = 0.f, pd = 0.f;
#pragma unroll
        for (int q = 0; q < 4; q++) {
            float4 xv = *(const float4*)&o1[r * 260 + seg * 16 + q * 4];
            float4 sv = *(const float4*)&a2s[seg * 16 + q * 4];
            float4 dv = *(const float4*)&a2d[seg * 16 + q * 4];
            ps += xv.x * sv.x + xv.y * sv.y + xv.z * sv.z + xv.w * sv.w;
            pd += xv.x * dv.x + xv.y * dv.y + xv.z * dv.z + xv.w * dv.w;
        }
        dred[(r * 16 + seg) * 2]     = ps;
        dred[(r * 16 + seg) * 2 + 1] = pd;
    }
    // OW2 = out1_block @ W2 : wave (mt = wv&1, nt = wv>>1), 8 k-steps
    {
        const int mt = wv & 1, nt = wv >> 1;
        f32x4 acc = zero;
        for (int k2 = 0; k2 < 8; ++k2) {
            int kc = k2 * 32 + g * 8;
            const float* op = &o1[(mt * 16 + li) * 260 + kc];
            float4 v0 = *(const float4*)op;
            float4 v1 = *(const float4*)(op + 4);
            s16x8 aa;
            aa[0] = (short)f2bf(v0.x); aa[1] = (short)f2bf(v0.y);
            aa[2] = (short)f2bf(v0.z); aa[3] = (short)f2bf(v0.w);
            aa[4] = (short)f2bf(v1.x); aa[5] = (short)f2bf(v1.y);
            aa[6] = (short)f2bf(v1.z); aa[7] = (short)f2bf(v1.w);
            s16x8 bb = *(const s16x8*)&W2T[(size_t)(nt * 16 + li) * NH + kc];
            acc = __builtin_amdgcn_mfma_f32_16x16x32_bf16(aa, bb, acc, 0, 0, 0);
        }
        int c = nt * 16 + li;
        uint2 pk;
        pk.x = (u32)f2bf(acc[0]) | ((u32)f2bf(acc[1]) << 16);
        pk.y = (u32)f2bf(acc[2]) | ((u32)f2bf(acc[3]) << 16);
        *(uint2*)&OW2T[((size_t)b * NC + c) * NN + i0 + mt * 16 + g * 4] = pk;
    }
    __syncthreads();
    if (t < 64) {              // reduce dots partials -> FS2/FD2
        int r = t & 31, which = t >> 5;
        float s = 0.f;
#pragma unroll
        for (int seg = 0; seg < 16; ++seg) s += dred[(r * 16 + seg) * 2 + which];
        if (which == 0) FS2[(b << 11) + i0 + r] = s * LOG2E;
        else            FD2[(b << 11) + i0 + r] = s * LOG2E;
    }
#undef LOADS1
#undef WRITEB1
}

// ---- layer2 spmm: node = rsc2 * W2mat @ OW2 + b2; graph partials -----------
__global__ __launch_bounds__(512) void kspmm2(
    const u32* __restrict__ bm32, const float* __restrict__ FS,
    const float* __restrict__ FD, const float* __restrict__ dvec,
    const u16* __restrict__ OW2T, const float* __restrict__ b2,
    float* __restrict__ node, float* __restrict__ gpart) {
    const int b = blockIdx.y;
    const int i0 = blockIdx.x * 32;
    const int t = threadIdx.x;
    const int l = t & 63, wv = t >> 6;
    const int g = l >> 4, li = l & 15;
    const int kf = wv >> 2;
    const int cf = wv & 3;

    __shared__ __attribute__((aligned(16))) u16 ob[2][64][64];
    __shared__ __attribute__((aligned(16))) u16 wb2[2][32][64];
    __shared__ __attribute__((aligned(16))) float tl2[32][68];
    __shared__ float rsred[16][32];
    __shared__ float rscl[32];

    const int orow = t >> 3;               // 0..63
    const int oseg = (t & 7) * 8;          // u16 col base
    const int wr = t & 31;
    const int wc = (t >> 5) * 4;

    const int grow = i0 + wr;
    const float fs_r = FS[(b << 11) + grow];
    const float* FDb = FD + (b << 11);
    const float* Db  = dvec + (b << 11);
    const u32* bmrow = bm32 + ((size_t)((b << 11) + grow)) * 64;
    const u16* Ob = OW2T + (size_t)b * NC * NN;

    int4 ov; float4 fdv, djv; u32 wbits; int jj;
    float rs_acc = 0.f;

#define LOADS2(K0_) { \
    ov = *(const int4*)(Ob + (size_t)orow * NN + (K0_) + oseg); \
    fdv = *(const float4*)&FDb[(K0_) + wc]; \
    djv = *(const float4*)&Db[(K0_) + wc]; \
    wbits = bmrow[((K0_) + wc) >> 5] >> (wc & 31); \
    jj = (K0_) + wc; }

#define WRITEB2(BI_) { \
    *(int4*)&ob[BI_][orow][oseg ^ ((orow & 7) << 3)] = ov; \
    float fdq[4] = {fdv.x, fdv.y, fdv.z, fdv.w}; \
    float djq[4] = {djv.x, djv.y, djv.z, djv.w}; \
    u16 wq[4]; \
    _Pragma("unroll") \
    for (int q = 0; q < 4; q++) { \
        float s_ = fs_r + fdq[q]; \
        float e_ = exp2f(fmaxf(s_, 0.2f * s_)); \
        rs_acc += ((wbits >> q) & 1u) ? e_ : 0.f; \
        float w_ = e_ * djq[q]; \
        if (jj + q == grow) w_ *= 2.f; \
        wq[q] = ((wbits >> q) & 1u) ? f2bf(w_) : (u16)0; } \
    uint2 pk; \
    pk.x = (u32)wq[0] | ((u32)wq[1] << 16); \
    pk.y = (u32)wq[2] | ((u32)wq[3] << 16); \
    *(uint2*)&wb2[BI_][wr][wc ^ ((wr & 7) << 3)] = pk; }

    f32x4 zero = {0.f, 0.f, 0.f, 0.f};
    f32x4 acc0 = zero, acc1 = zero;

    LOADS2(0); WRITEB2(0);
    for (int k = 0; k < NK; ++k) {
        const int nxt = k + 1;
        if (nxt < NK) LOADS2(nxt * KS);
        __syncthreads();
        const int cb = k & 1;
        const int kc = kf * 32 + g * 8;
        const int swr = (li & 7) << 3;
        s16x8 af0 = *(const s16x8*)&wb2[cb][li]     [kc ^ swr];
        s16x8 af1 = *(const s16x8*)&wb2[cb][16 + li][kc ^ swr];
        s16x8 bfr = *(const s16x8*)&ob[cb][cf * 16 + li][kc ^ swr];
        acc0 = __builtin_amdgcn_mfma_f32_16x16x32_bf16(af0, bfr, acc0, 0, 0, 0);
        acc1 = __builtin_amdgcn_mfma_f32_16x16x32_bf16(af1, bfr, acc1, 0, 0, 0);
        if (nxt < NK) WRITEB2(nxt & 1);
    }
    rsred[t >> 5][wr] = rs_acc;
    __syncthreads();
    if (t < 32) {
        float rs = 0.f;
#pragma unroll
        for (int s = 0; s < 16; ++s) rs += rsred[s][t];
        rscl[t] = Db[i0 + t] / rs;
    }
    if (wv < 4) {
#pragma unroll
        for (int r = 0; r < 4; r++) {
            tl2[g * 4 + r]     [cf * 16 + li] = acc0[r];
            tl2[16 + g * 4 + r][cf * 16 + li] = acc1[r];
        }
    }
    __syncthreads();
    if (wv >= 4) {
#pragma unroll
        for (int r = 0; r < 4; r++) {
            tl2[g * 4 + r]     [cf * 16 + li] += acc0[r];
            tl2[16 + g * 4 + r][cf * 16 + li] += acc1[r];
        }
    }
    __syncthreads();
    {   // scale + bias, store node, write back for graph partial
        int r = t >> 4, c0 = (t & 15) * 4;
        float rsc = rscl[r];
        float4 v = *(const float4*)&tl2[r][c0];
        float4 bb = *(const float4*)&b2[c0];
        v.x = v.x * rsc + bb.x; v.y = v.y * rsc + bb.y;
        v.z = v.z * rsc + bb.z; v.w = v.w * rsc + bb.w;
        *(float4*)&node[((size_t)(b << 11) + i0 + r) * NC + c0] = v;
        *(float4*)&tl2[r][c0] = v;
    }
    __syncthreads();
    if (t < NC) {
        float s = 0.f;
#pragma unroll
        for (int r = 0; r < 32; ++r) s += tl2[r][t];
        gpart[(((size_t)b * (NN / 32)) + blockIdx.x) * NC + t] = s;
    }
#undef LOADS2
#undef WRITEB2
}

// ---- graph scores: reduce per-block partials -------------------------------
__global__ void kgraph2(const float* __restrict__ gpart, float* __restrict__ graph) {
    int b = blockIdx.x;
    int c = threadIdx.x & 63, ch = threadIdx.x >> 6;
    float s = 0.f;
    for (int p = ch; p < NN / 32; p += 4)
        s += gpart[(((size_t)b * (NN / 32)) + p) * NC + c];
    __shared__ float red[4][64];
    red[ch][c] = s;
    __syncthreads();
    if (ch == 0) graph[b * NC + c] = red[0][c] + red[1][c] + red[2][c] + red[3][c];
}

extern "C" void kernel_launch(void* const* d_in, const int* in_sizes, int n_in,
                              void* d_out, int out_size, void* d_ws, size_t ws_size,
                              hipStream_t stream) {
    const float* X   = (const float*)d_in[0];
    const float* A   = (const float*)d_in[1];
    const float* a1s = (const float*)d_in[2];
    const float* a1d = (const float*)d_in[3];
    const float* W1  = (const float*)d_in[4];
    const float* b1  = (const float*)d_in[5];
    const float* a2s = (const float*)d_in[6];
    const float* a2d = (const float*)d_in[7];
    const float* W2  = (const float*)d_in[8];
    const float* b2  = (const float*)d_in[9];

    float* node  = (float*)d_out;                 // [4][2048][64]
    float* graph = node + (size_t)NB * NN * NC;   // [4][64]

    char* w = (char*)d_ws;
    float* FS1  = (float*)w; w += NB * NN * 4;
    float* FD1  = (float*)w; w += NB * NN * 4;
    float* FS2  = (float*)w; w += NB * NN * 4;
    float* FD2  = (float*)w; w += NB * NN * 4;
    float* dvec = (float*)w; w += NB * NN * 4;
    u64*  bm    = (u64*)w;  w += (size_t)NB * NN * 32 * 8;    // 2 MB
    u16*  XT    = (u16*)w;  w += (size_t)NB * NF * NN * 2;    // 2 MB
    u16*  OW2T  = (u16*)w;  w += (size_t)NB * NC * NN * 2;    // 1 MB
    u16*  W1T   = (u16*)w;  w += NH * NF * 2;
    u16*  W2T   = (u16*)w;  w += NC * NH * 2;
    float* gpart = (float*)w; w += (size_t)NB * (NN / 32) * NC * 4;  // 64 KB

    kprep   <<<dim3(33, NB), 256, 0, stream>>>(X, a1s, a1d, W1, W2, XT, W1T, W2T,
                                               FS1, FD1);
    kstats1 <<<NB * NN, 256, 0, stream>>>(A, dvec, bm);
    kspmm1  <<<dim3(NN / 32, NB), 512, 0, stream>>>((const u32*)bm, FS1, FD1, dvec,
                                                    XT, W1T, W2T, b1, a2s, a2d,
                                                    FS2, FD2, OW2T);
    kspmm2  <<<dim3(NN / 32, NB), 512, 0, stream>>>((const u32*)bm, FS2, FD2, dvec,
                                                    OW2T, b2, node, gpart);
    kgraph2 <<<NB, 256, 0, stream>>>(gpart, graph);
}